// Round 2
// baseline (840.599 us; speedup 1.0000x reference)
//
#include <hip/hip_runtime.h>
#include <cmath>

// Problem constants (N=2, S=512, C=512, H=W=50, OUT=7, RATIO=2)
#define NIMG 2
#define SPROP 512
#define NROI 1024          // NIMG*SPROP
#define CCH 512
#define FH 50
#define FW 50
#define K1 25088           // CCH*7*7
#define HID 1024
#define NCLS 21
#define NDET 100
#define IMGSZ 800.0f
#define LOGMAX 4.135166556742356f   // log(1000/16)
#define MCAND 10240        // SPROP*(NCLS-1)
#define ZSPLIT 8
#define KCHUNK 3136        // K1/ZSPLIT
#define ZSPLIT2 4
#define KCHUNK2 256        // HID/ZSPLIT2

typedef unsigned short u16;
typedef __attribute__((ext_vector_type(8))) short short8;
typedef __attribute__((ext_vector_type(4))) float f32x4;
typedef __attribute__((ext_vector_type(16))) float f32x16;

__device__ __forceinline__ u16 f2bf(float x) {        // RTNE fp32 -> bf16
  unsigned int u = __float_as_uint(x);
  u += 0x7fffu + ((u >> 16) & 1u);
  return (u16)(u >> 16);
}
__device__ __forceinline__ float bf2f(u16 h) {
  return __uint_as_float(((unsigned int)h) << 16);
}

// ------------------------------------------------------------ ROI align
template <bool BF16OUT>
__global__ __launch_bounds__(256) void roi_kernel(
    const float* __restrict__ feat, const float* __restrict__ props,
    float* __restrict__ X, u16* __restrict__ Xhi, u16* __restrict__ Xlo) {
  const int r = blockIdx.x;
  const int n = r >> 9;
  const int tid = threadIdx.x;
  __shared__ float tile[32][256];   // 32 ch x (16x16 px) = 32 KB
  __shared__ int sy0[14], sy1[14], sx0[14], sx1[14];
  __shared__ float sly[14], slx[14], svy[14], svx[14];

  const float p0 = props[r * 4 + 0] * 0.0625f;
  const float p1 = props[r * 4 + 1] * 0.0625f;
  const float p2 = props[r * 4 + 2] * 0.0625f;
  const float p3 = props[r * 4 + 3] * 0.0625f;
  const float bw = fmaxf(p2 - p0, 1.0f) / 7.0f;
  const float bh = fmaxf(p3 - p1, 1.0f) / 7.0f;

  if (tid < 14) {
    const int j = tid;
    const float g = (float)(j >> 1) + ((float)(j & 1) + 0.5f) * 0.5f;
    float y = p1 + g * bh;
    svy[j] = (y > -1.0f && y < (float)FH) ? 1.0f : 0.0f;
    float yc = fminf(fmaxf(y, 0.0f), (float)(FH - 1));
    int y0 = (int)floorf(yc);
    sy0[j] = y0; sy1[j] = min(y0 + 1, FH - 1); sly[j] = yc - (float)y0;
    float x = p0 + g * bw;
    svx[j] = (x > -1.0f && x < (float)FW) ? 1.0f : 0.0f;
    float xc = fminf(fmaxf(x, 0.0f), (float)(FW - 1));
    int x0 = (int)floorf(xc);
    sx0[j] = x0; sx1[j] = min(x0 + 1, FW - 1); slx[j] = xc - (float)x0;
  }
  __syncthreads();
  const int ymin = sy0[0], xmin = sx0[0];
  const float* fb = feat + (size_t)n * CCH * (FH * FW);

  for (int cc = 0; cc < 16; ++cc) {
    const int c0 = cc * 32;
#pragma unroll
    for (int e = 0; e < 32; ++e) {
      const int idx = tid + e * 256;
      const int c = idx >> 8, p = idx & 255;
      const int gy = min(ymin + (p >> 4), FH - 1);
      const int gx = min(xmin + (p & 15), FW - 1);
      tile[c][p] = fb[(size_t)(c0 + c) * (FH * FW) + gy * FW + gx];
    }
    __syncthreads();
#pragma unroll
    for (int e = 0; e < 7; ++e) {
      const int idx = tid + e * 256;
      if (idx < 1568) {
        const int c = idx / 49;
        const int s = idx - c * 49;
        const int oy = s / 7, ox = s - (s / 7) * 7;
        float acc = 0.0f;
#pragma unroll
        for (int sy = 0; sy < 2; ++sy) {
          const int yj = oy * 2 + sy;
          const int py0 = sy0[yj] - ymin, py1 = sy1[yj] - ymin;
          const float ly = sly[yj], vy = svy[yj];
#pragma unroll
          for (int sx = 0; sx < 2; ++sx) {
            const int xj = ox * 2 + sx;
            const int px0 = sx0[xj] - xmin, px1 = sx1[xj] - xmin;
            const float lx = slx[xj], vx = svx[xj];
            const float f00 = tile[c][py0 * 16 + px0];
            const float f01 = tile[c][py0 * 16 + px1];
            const float f10 = tile[c][py1 * 16 + px0];
            const float f11 = tile[c][py1 * 16 + px1];
            float v = f00 * (1.0f - ly) * (1.0f - lx) + f01 * (1.0f - ly) * lx +
                      f10 * ly * (1.0f - lx) + f11 * ly * lx;
            acc += v * (vy * vx);
          }
        }
        const float v = acc * 0.25f;
        const size_t k = (size_t)r * K1 + (size_t)(c0 + c) * 49 + s;
        if (BF16OUT) {
          const u16 h = f2bf(v);
          Xhi[k] = h;
          Xlo[k] = f2bf(v - bf2f(h));
        } else {
          X[k] = v;
        }
      }
    }
    __syncthreads();
  }
}

// ------------------------- w -> hi/lo bf16, transposed to [n][k]
// Generic over K dimension (w1: K1 x HID, w2: HID x HID), both [k][n] in.
template <int KDIM>
__global__ __launch_bounds__(256) void convw_kernel(
    const float* __restrict__ w, u16* __restrict__ Wh, u16* __restrict__ Wl) {
  __shared__ u16 sh[64][65], sl[64][65];
  const int k0 = blockIdx.x * 64;
  const int n0 = blockIdx.y * 64;
  const int t = threadIdx.x;
#pragma unroll
  for (int e = 0; e < 16; ++e) {
    const int idx = t + e * 256;
    const int kl = idx >> 6, nl = idx & 63;
    const float v = w[(size_t)(k0 + kl) * HID + n0 + nl];
    const u16 h = f2bf(v);
    sh[kl][nl] = h;
    sl[kl][nl] = f2bf(v - bf2f(h));
  }
  __syncthreads();
#pragma unroll
  for (int e = 0; e < 16; ++e) {
    const int idx = t + e * 256;
    const int nl = idx >> 6, kl = idx & 63;
    Wh[(size_t)(n0 + nl) * KDIM + k0 + kl] = sh[kl][nl];
    Wl[(size_t)(n0 + nl) * KDIM + k0 + kl] = sl[kl][nl];
  }
}

// --------------- split-bf16 MFMA GEMM (32x32x16), generic K-stride / K-chunk
// Round-9 rewrite, driven by r8 counters (MfmaUtil 38.6, Occupancy 19.4,
// FETCH 490 MB vs 205 unique, BANK_CONFLICT 12.8M):
//  * 512-thread blocks, 8 waves of 32x64 on the same 128x128 tile ->
//    16 waves/CU (was 8), no extra CP traffic.
//  * XCD swizzle (T1): z = flat%8 so each XCD's 64 resident blocks stream one
//    K-chunk z-slice through its private L2 -> FETCH ~unique (~240 MB).
//  * LDS stride 32 u16 (16B-aligned) + 16B-chunk XOR swizzle
//    chunk' = chunk ^ ((row>>1)&3), same on write & read -> uniform 8 req/bank
//    (minimal) for both uint4 writes and b128 reads. LDS 40->32 KB/block.
//  * 2-deep register prefetch: ds_write of set A waits only set A's loads
//    (compiler emits counted vmcnt from the reg dep) -> ~2 compute phases of
//    latency coverage.
// A/B frag: [row = lane&31][k = (lane>>5)*8 + j].
// C/D: col = lane&31, row = (reg&3) + 8*(reg>>2) + 4*(lane>>5)  [m74/m101].
template <int KS, int KCH, bool SWZ>
__global__ __launch_bounds__(512, 4) void gemm_mfma_split(
    const u16* __restrict__ Ahg, const u16* __restrict__ Alg,
    const u16* __restrict__ Bhg, const u16* __restrict__ Blg,
    float* __restrict__ CP) {
  __shared__ u16 Ah[128][32], Al[128][32], Bh[128][32], Bl[128][32];
  const int tid = threadIdx.x;
  const int lane = tid & 63;
  const int wv = tid >> 6;           // 0..7
  const int wm = (wv >> 1) << 5;     // row band {0,32,64,96}
  const int wn = (wv & 1) << 6;      // col half {0,64}

  int bx = blockIdx.x, by = blockIdx.y, bz = blockIdx.z;
  if (SWZ) {
    // grid must be 8x8x8: XCD (= flat%8 under round-robin dispatch) <-> z.
    const int f = blockIdx.x + ((blockIdx.y + (blockIdx.z << 3)) << 3);
    bz = f & 7;
    const int u = f >> 3;
    bx = u & 7;
    by = u >> 3;
  }
  const int mT = by << 7;
  const int nT = bx << 7;
  const int kz = bz * KCH;
  const int kend = kz + KCH;

  // staging: thread -> (row sr, 16B chunk tid&3), one uint4 per array
  const int sr = tid >> 2;                                  // 0..127
  const int sq = (tid & 3) << 3;                            // src col (u16)
  const int scw = (((tid & 3) ^ ((sr >> 1) & 3)) << 3);     // swizzled dst col
  const size_t aoff = (size_t)(mT + sr) * KS;
  const size_t boff = (size_t)(nT + sr) * KS;

  f32x16 acc[2];
#pragma unroll
  for (int j = 0; j < 2; ++j)
#pragma unroll
    for (int e = 0; e < 16; ++e) acc[j][e] = 0.0f;

  const int fm = lane & 31;          // row within 32-tile
  const int fh = lane >> 5;          // k-subgroup (0/1)
  const int vswz = (fm >> 1) & 3;    // read-side swizzle (row-derived)

  // prologue: 2-deep staging (set R = k, set S = k+32)
  uint4 rA = *(const uint4*)(Ahg + aoff + kz + sq);
  uint4 rL = *(const uint4*)(Alg + aoff + kz + sq);
  uint4 rB = *(const uint4*)(Bhg + boff + kz + sq);
  uint4 rM = *(const uint4*)(Blg + boff + kz + sq);
  uint4 sA = *(const uint4*)(Ahg + aoff + kz + 32 + sq);
  uint4 sL = *(const uint4*)(Alg + aoff + kz + 32 + sq);
  uint4 sB = *(const uint4*)(Bhg + boff + kz + 32 + sq);
  uint4 sM = *(const uint4*)(Blg + boff + kz + 32 + sq);

  auto compute = [&]() {
#pragma unroll
    for (int kh = 0; kh < 2; ++kh) {
      const int cA = ((((kh << 1) | fh) ^ vswz) << 3);
      const short8 fah = *(const short8*)(&Ah[wm + fm][cA]);
      const short8 fal = *(const short8*)(&Al[wm + fm][cA]);
      short8 fbh[2], fbl[2];
      fbh[0] = *(const short8*)(&Bh[wn + fm][cA]);
      fbh[1] = *(const short8*)(&Bh[wn + 32 + fm][cA]);
      fbl[0] = *(const short8*)(&Bl[wn + fm][cA]);
      fbl[1] = *(const short8*)(&Bl[wn + 32 + fm][cA]);
#pragma unroll
      for (int tj = 0; tj < 2; ++tj) {
        acc[tj] = __builtin_amdgcn_mfma_f32_32x32x16_bf16(fah, fbh[tj], acc[tj], 0, 0, 0);
        acc[tj] = __builtin_amdgcn_mfma_f32_32x32x16_bf16(fah, fbl[tj], acc[tj], 0, 0, 0);
        acc[tj] = __builtin_amdgcn_mfma_f32_32x32x16_bf16(fal, fbh[tj], acc[tj], 0, 0, 0);
      }
    }
  };

  for (int kb = kz; kb < kend; kb += 64) {
    // ---- half 1: consume set R (tile kb)
    *(uint4*)(&Ah[sr][scw]) = rA;     // waits only set-R loads (counted vmcnt)
    *(uint4*)(&Al[sr][scw]) = rL;
    *(uint4*)(&Bh[sr][scw]) = rB;
    *(uint4*)(&Bl[sr][scw]) = rM;
    __syncthreads();
    const int kn1 = (kb + 64 < kend) ? kb + 64 : kz;   // fallback: safe addr
    rA = *(const uint4*)(Ahg + aoff + kn1 + sq);
    rL = *(const uint4*)(Alg + aoff + kn1 + sq);
    rB = *(const uint4*)(Bhg + boff + kn1 + sq);
    rM = *(const uint4*)(Blg + boff + kn1 + sq);
    compute();
    __syncthreads();
    // ---- half 2: consume set S (tile kb+32)
    *(uint4*)(&Ah[sr][scw]) = sA;
    *(uint4*)(&Al[sr][scw]) = sL;
    *(uint4*)(&Bh[sr][scw]) = sB;
    *(uint4*)(&Bl[sr][scw]) = sM;
    __syncthreads();
    const int kn2 = (kb + 96 < kend) ? kb + 96 : kz;
    sA = *(const uint4*)(Ahg + aoff + kn2 + sq);
    sL = *(const uint4*)(Alg + aoff + kn2 + sq);
    sB = *(const uint4*)(Bhg + boff + kn2 + sq);
    sM = *(const uint4*)(Blg + boff + kn2 + sq);
    compute();
    __syncthreads();
  }

  float* Cp = CP + (size_t)bz * ((size_t)NROI * HID);   // bz: swizzled!
  const int ccol = nT + wn + fm;
  const int rbase = mT + wm + (fh << 2);
#pragma unroll
  for (int tj = 0; tj < 2; ++tj)
#pragma unroll
    for (int rg = 0; rg < 16; ++rg) {
      const int row = rbase + (rg & 3) + 8 * (rg >> 2);
      Cp[(size_t)row * HID + ccol + tj * 32] = acc[tj][rg];
    }
}

// ------------------------------------------------------- FC1 fallback (fp32)
__global__ __launch_bounds__(256) void gemm1_kernel(
    const float* __restrict__ A, const float* __restrict__ B,
    float* __restrict__ CP) {
  __shared__ float As[16][68];
  __shared__ float Bs[16][68];
  const int tid = threadIdx.x;
  const int mTile = blockIdx.y << 6;
  const int nTile = blockIdx.x << 6;
  const int k0 = blockIdx.z * KCHUNK;
  const int ty = tid >> 4, tx = tid & 15;
  const int ar = tid >> 2, ac = (tid & 3) << 2;
  const int br = tid >> 4, bcl = (tid & 15) << 2;
  float acc[4][4] = {};

  for (int kb = k0; kb < k0 + KCHUNK; kb += 16) {
    const float4 av = *(const float4*)(A + (size_t)(mTile + ar) * K1 + kb + ac);
    const float4 bv = *(const float4*)(B + (size_t)(kb + br) * HID + nTile + bcl);
    As[ac + 0][ar] = av.x; As[ac + 1][ar] = av.y;
    As[ac + 2][ar] = av.z; As[ac + 3][ar] = av.w;
    *(float4*)(&Bs[br][bcl]) = bv;
    __syncthreads();
#pragma unroll
    for (int kk = 0; kk < 16; ++kk) {
      const float4 a4 = *(const float4*)(&As[kk][ty << 2]);
      const float4 b4 = *(const float4*)(&Bs[kk][tx << 2]);
      const float aa[4] = {a4.x, a4.y, a4.z, a4.w};
      const float bb4[4] = {b4.x, b4.y, b4.z, b4.w};
#pragma unroll
      for (int i = 0; i < 4; ++i)
#pragma unroll
        for (int j = 0; j < 4; ++j)
          acc[i][j] = fmaf(aa[i], bb4[j], acc[i][j]);
    }
    __syncthreads();
  }
  float* Cp = CP + (size_t)blockIdx.z * (HID * NROI);
#pragma unroll
  for (int i = 0; i < 4; ++i) {
    *(float4*)(Cp + (size_t)(mTile + (ty << 2) + i) * HID + nTile + (tx << 2)) =
        make_float4(acc[i][0], acc[i][1], acc[i][2], acc[i][3]);
  }
}

// reduce 8 K-partials + bias + relu -> H1 as split-bf16 (feeds FC2 MFMA)
__global__ __launch_bounds__(256) void bias_relu_bf16_kernel(
    const float* __restrict__ CP, const float* __restrict__ b1,
    u16* __restrict__ H1h, u16* __restrict__ H1l) {
  const int idx = blockIdx.x * 256 + threadIdx.x;
  float v = b1[idx & (HID - 1)];
#pragma unroll
  for (int z = 0; z < ZSPLIT; ++z) v += CP[(size_t)z * (HID * NROI) + idx];
  v = fmaxf(v, 0.0f);
  const u16 h = f2bf(v);
  H1h[idx] = h;
  H1l[idx] = f2bf(v - bf2f(h));
}

// fp32 variant for the fallback path
__global__ __launch_bounds__(256) void bias_relu_f32_kernel(
    const float* __restrict__ CP, const float* __restrict__ b1,
    float* __restrict__ H1) {
  const int idx = blockIdx.x * 256 + threadIdx.x;
  float v = b1[idx & (HID - 1)];
#pragma unroll
  for (int z = 0; z < ZSPLIT; ++z) v += CP[(size_t)z * (HID * NROI) + idx];
  H1[idx] = fmaxf(v, 0.0f);
}

// reduce 4 K-partials of FC2 + bias + relu -> H2 fp32
__global__ __launch_bounds__(256) void bias_relu2_kernel(
    const float* __restrict__ CP2, const float* __restrict__ b2,
    float* __restrict__ H2) {
  const int idx = blockIdx.x * 256 + threadIdx.x;
  float v = b2[idx & (HID - 1)];
#pragma unroll
  for (int z = 0; z < ZSPLIT2; ++z) v += CP2[(size_t)z * (HID * NROI) + idx];
  H2[idx] = fmaxf(v, 0.0f);
}

// ------------------------------------------------------------- FC2 (K=1024)
// fp32 fallback only (bf16 path uses gemm_mfma_split<HID, KCHUNK2, false>)
__global__ __launch_bounds__(256) void gemm2_kernel(
    const float* __restrict__ A, const float* __restrict__ B,
    const float* __restrict__ bias, float* __restrict__ C) {
  __shared__ float As[16][68];
  __shared__ float Bs[16][68];
  const int tid = threadIdx.x;
  const int mTile = blockIdx.y << 6;
  const int nTile = blockIdx.x << 6;
  const int ty = tid >> 4, tx = tid & 15;
  const int ar = tid >> 2, ac = (tid & 3) << 2;
  const int br = tid >> 4, bcl = (tid & 15) << 2;
  float acc[4][4] = {};

  for (int kb = 0; kb < HID; kb += 16) {
    const float4 av = *(const float4*)(A + (size_t)(mTile + ar) * HID + kb + ac);
    const float4 bv = *(const float4*)(B + (size_t)(kb + br) * HID + nTile + bcl);
    As[ac + 0][ar] = av.x; As[ac + 1][ar] = av.y;
    As[ac + 2][ar] = av.z; As[ac + 3][ar] = av.w;
    *(float4*)(&Bs[br][bcl]) = bv;
    __syncthreads();
#pragma unroll
    for (int kk = 0; kk < 16; ++kk) {
      const float4 a4 = *(const float4*)(&As[kk][ty << 2]);
      const float4 b4 = *(const float4*)(&Bs[kk][tx << 2]);
      const float aa[4] = {a4.x, a4.y, a4.z, a4.w};
      const float bb4[4] = {b4.x, b4.y, b4.z, b4.w};
#pragma unroll
      for (int i = 0; i < 4; ++i)
#pragma unroll
        for (int j = 0; j < 4; ++j)
          acc[i][j] = fmaf(aa[i], bb4[j], acc[i][j]);
    }
    __syncthreads();
  }
#pragma unroll
  for (int i = 0; i < 4; ++i) {
#pragma unroll
    for (int j = 0; j < 4; ++j) {
      float v = acc[i][j] + bias[nTile + (tx << 2) + j];
      acc[i][j] = fmaxf(v, 0.0f);
    }
    *(float4*)(C + (size_t)(mTile + (ty << 2) + i) * HID + nTile + (tx << 2)) =
        make_float4(acc[i][0], acc[i][1], acc[i][2], acc[i][3]);
  }
}

// ------------------- heads: cls+box dots, softmax, decode, candidate arrays
// Candidate layout is CLASS-MAJOR: index = n*MCAND + (k-1)*SPROP + s
__global__ __launch_bounds__(128) void heads_kernel(
    const float* __restrict__ H2m, const float* __restrict__ wc,
    const float* __restrict__ bc, const float* __restrict__ wb,
    const float* __restrict__ bb, const float* __restrict__ props,
    float* __restrict__ BX2, float* __restrict__ NB2,
    float* __restrict__ LV2) {
  const int r = blockIdx.x;
  const int tid = threadIdx.x;
  __shared__ float hrow[HID];
  __shared__ float vals[112];
  __shared__ float red[2];

  for (int i = tid; i < HID; i += 128) hrow[i] = H2m[(size_t)r * HID + i];
  __syncthreads();

  if (tid < 105) {
    float acc;
    if (tid < NCLS) {
      acc = bc[tid];
      for (int kk = 0; kk < HID; ++kk) acc = fmaf(hrow[kk], wc[kk * NCLS + tid], acc);
    } else {
      const int j = tid - NCLS;
      acc = bb[j];
      for (int kk = 0; kk < HID; ++kk) acc = fmaf(hrow[kk], wb[kk * (NCLS * 4) + j], acc);
    }
    vals[tid] = acc;
  }
  __syncthreads();

  if (tid == 0) {
    float m = vals[0];
    for (int k = 1; k < NCLS; ++k) m = fmaxf(m, vals[k]);
    float s = 0.0f;
    for (int k = 0; k < NCLS; ++k) s += expf(vals[k] - m);
    red[0] = m;
    red[1] = 1.0f / s;
  }
  __syncthreads();

  if (tid >= 1 && tid <= 20) {
    const int k = tid;
    const float prob = expf(vals[k] - red[0]) * red[1];

    const float px1 = props[r * 4 + 0], py1 = props[r * 4 + 1];
    const float px2 = props[r * 4 + 2], py2 = props[r * 4 + 3];
    const float pw = px2 - px1, ph = py2 - py1;
    const float pcx = px1 + 0.5f * pw, pcy = py1 + 0.5f * ph;

    const float dx = vals[NCLS + k * 4 + 0] / 10.0f;
    const float dy = vals[NCLS + k * 4 + 1] / 10.0f;
    const float dw = fminf(vals[NCLS + k * 4 + 2] / 5.0f, LOGMAX);
    const float dh = fminf(vals[NCLS + k * 4 + 3] / 5.0f, LOGMAX);

    const float cx = dx * pw + pcx, cy = dy * ph + pcy;
    const float w = expf(dw) * pw, h = expf(dh) * ph;
    float b0 = cx - 0.5f * w, b1c = cy - 0.5f * h;
    float b2 = cx + 0.5f * w, b3 = cy + 0.5f * h;
    b0 = fminf(fmaxf(b0, 0.0f), IMGSZ);
    b1c = fminf(fmaxf(b1c, 0.0f), IMGSZ);
    b2 = fminf(fmaxf(b2, 0.0f), IMGSZ);
    b3 = fminf(fmaxf(b3, 0.0f), IMGSZ);

    const float wv = b2 - b0, hv = b3 - b1c;
    const bool valid = (prob > 0.05f) && (wv >= 0.01f) && (hv >= 0.01f);

    const int n = r >> 9, s = r & 511;
    const int cand = (k - 1) * SPROP + s;     // class-major
    const size_t bi = (size_t)n * MCAND + cand;
    const float off = (float)k * (IMGSZ + 1.0f);

    BX2[bi * 4 + 0] = b0; BX2[bi * 4 + 1] = b1c;
    BX2[bi * 4 + 2] = b2; BX2[bi * 4 + 3] = b3;
    NB2[bi * 4 + 0] = b0 + off; NB2[bi * 4 + 1] = b1c + off;
    NB2[bi * 4 + 2] = b2 + off; NB2[bi * 4 + 3] = b3 + off;
    LV2[bi] = valid ? prob : -1.0f;
  }
}

// ---------------------------------------------- per-(image,class) greedy NMS
// Cross-class IoU == 0 (801*k offsets), so the global greedy restricted to a
// class equals the standalone per-class greedy (proved by induction on picks).
// One wave per (n,c): 512 slots in registers, barrier-free serial loop.
template <int CTRL>
__device__ __forceinline__ void red2(float& v, int& ix) {
  const float tv = __int_as_float(__builtin_amdgcn_update_dpp(
      (int)0xC0000000, __float_as_int(v), CTRL, 0xf, 0xf, false));
  const int ti = __builtin_amdgcn_update_dpp(0x7fffffff, ix, CTRL, 0xf, 0xf, false);
  if (tv > v || (tv == v && ti < ix)) { v = tv; ix = ti; }
}
__device__ __forceinline__ void wave_red2(float& v, int& ix) {
  red2<0x111>(v, ix);  // row_shr:1
  red2<0x112>(v, ix);  // row_shr:2
  red2<0x114>(v, ix);  // row_shr:4
  red2<0x118>(v, ix);  // row_shr:8
  red2<0x142>(v, ix);  // row_bcast:15
  red2<0x143>(v, ix);  // row_bcast:31 -> lane 63 holds winner
}

__global__ __launch_bounds__(64) void nms_class_kernel(
    const float* __restrict__ NB2, const float* __restrict__ LV2,
    float* __restrict__ ksg, int* __restrict__ kig, int* __restrict__ cntg) {
  const int bid = blockIdx.x;           // n*20 + c
  const int lane = threadIdx.x;         // 0..63
  __shared__ float4 lbox[SPROP];        // winner-broadcast copy
  const size_t cb = (size_t)bid * SPROP;

  float lv[8], b0[8], b1[8], b2[8], b3[8], ar[8];
#pragma unroll
  for (int j = 0; j < 8; ++j) {
    const int s = lane + j * 64;
    lv[j] = LV2[cb + s];
    const float4 b = *(const float4*)(NB2 + (cb + s) * 4);
    b0[j] = b.x; b1[j] = b.y; b2[j] = b.z; b3[j] = b.w;
    ar[j] = (b.z - b.x) * (b.w - b.y);
    lbox[s] = b;
  }

  int cnt = 0;
  for (int d = 0; d < NDET; ++d) {
    float bv = -2.0f;
    int bix = 0x7fffffff;
#pragma unroll
    for (int j = 0; j < 8; ++j) {     // j asc => slot asc; strict > keeps lowest
      if (lv[j] > bv) { bv = lv[j]; bix = lane + j * 64; }
    }
    wave_red2(bv, bix);
    const float bv2 = __shfl(bv, 63);
    const int bix2 = __shfl(bix, 63);
    if (bv2 <= 0.05f) break;          // all remaining dead; wave-uniform

    if (lane == 0) {
      ksg[bid * NDET + cnt] = bv2;
      kig[bid * NDET + cnt] = bix2;   // slot within class (0..511)
    }
    ++cnt;

    const float4 wb = lbox[bix2];     // same-wave LDS write->read, waitcnt ok
    const float wa = (wb.z - wb.x) * (wb.w - wb.y);
#pragma unroll
    for (int j = 0; j < 8; ++j) {
      const float xx1 = fmaxf(wb.x, b0[j]);
      const float yy1 = fmaxf(wb.y, b1[j]);
      const float xx2 = fminf(wb.z, b2[j]);
      const float yy2 = fminf(wb.w, b3[j]);
      const float inter = fmaxf(xx2 - xx1, 0.0f) * fmaxf(yy2 - yy1, 0.0f);
      const float iou = inter / (wa + ar[j] - inter + 1e-9f);
      if (iou > 0.5f) lv[j] = -1.0f;
    }
  }
  if (lane == 0) cntg[bid] = cnt;
}

// ------------------------------- merge: top-100 by (score desc, flat-idx asc)
// Global greedy order == keeps sorted by packed priority (scores non-increasing
// along greedy; tied keeps are simultaneously live so argmax first-index rule
// = lowest flat idx). Rank-based selection: zero barriers in the hot loop.
__global__ __launch_bounds__(1024) void nms_merge_kernel(
    const float* __restrict__ ksg, const int* __restrict__ kig,
    const int* __restrict__ cntg, const float* __restrict__ BX2,
    float* __restrict__ out) {
  const int n = blockIdx.x;
  const int tid = threadIdx.x;
  __shared__ int cbase[21];
  __shared__ unsigned long long keys[2000];
  __shared__ float ssc[2000];
  __shared__ int sfl[2000];
  __shared__ float svals[NDET];
  __shared__ int sflat[NDET];

  if (tid == 0) {
    int acc = 0;
    for (int c = 0; c < 20; ++c) { cbase[c] = acc; acc += cntg[n * 20 + c]; }
    cbase[20] = acc;
  }
  __syncthreads();
  const int T = cbase[20];     // <= 2000

  for (int idx = tid; idx < 20 * NDET; idx += 1024) {
    const int c = idx / NDET, e = idx - (idx / NDET) * NDET;
    if (e < cntg[n * 20 + c]) {
      const int pos = cbase[c] + e;
      const float s = ksg[(n * 20 + c) * NDET + e];
      const int slot = kig[(n * 20 + c) * NDET + e];
      const int flat = slot * 20 + c;            // original flat candidate idx
      ssc[pos] = s;
      sfl[pos] = flat;
      keys[pos] = ((unsigned long long)__float_as_uint(s) << 32) |
                  (unsigned long long)(0xFFFFFFFFu - (unsigned)flat);
    }
  }
  __syncthreads();

  float msc[2]; int mfl[2]; unsigned long long mk[2]; int rank[2] = {0, 0};
  bool own[2];
#pragma unroll
  for (int e = 0; e < 2; ++e) {
    const int i = tid + e * 1024;
    own[e] = (i < T);
    if (own[e]) { mk[e] = keys[i]; msc[e] = ssc[i]; mfl[e] = sfl[i]; }
  }
  for (int i = 0; i < T; ++i) {        // LDS broadcast read per iteration
    const unsigned long long k = keys[i];
    if (own[0] && k > mk[0]) ++rank[0];
    if (own[1] && k > mk[1]) ++rank[1];
  }
#pragma unroll
  for (int e = 0; e < 2; ++e)
    if (own[e] && rank[e] < NDET) { svals[rank[e]] = msc[e]; sflat[rank[e]] = mfl[e]; }
  __syncthreads();

  if (tid < NDET) {
    const int m = (T < NDET) ? T : NDET;
    const bool keep = tid < m;
    float sv = 0.0f;
    float4 bx4 = make_float4(0.0f, 0.0f, 0.0f, 0.0f);
    float label = 0.0f;
    if (keep) {
      sv = svals[tid];
      const int flat = sflat[tid];
      const int c = flat % 20, s = flat / 20;
      bx4 = *(const float4*)(BX2 + ((size_t)(n * 20 + c) * SPROP + s) * 4);
      label = (float)(c + 1);
    }
    out[(n * NDET + tid) * 4 + 0] = bx4.x;
    out[(n * NDET + tid) * 4 + 1] = bx4.y;
    out[(n * NDET + tid) * 4 + 2] = bx4.z;
    out[(n * NDET + tid) * 4 + 3] = bx4.w;
    out[NIMG * NDET * 4 + n * NDET + tid] = sv;
    out[NIMG * NDET * 4 + NIMG * NDET + n * NDET + tid] = label;
  }
}

// ---------------------------------------------------------------- launcher
extern "C" void kernel_launch(void* const* d_in, const int* in_sizes, int n_in,
                              void* d_out, int out_size, void* d_ws, size_t ws_size,
                              hipStream_t stream) {
  const float* features  = (const float*)d_in[0];
  const float* proposals = (const float*)d_in[1];
  const float* w1 = (const float*)d_in[2];
  const float* b1 = (const float*)d_in[3];
  const float* w2 = (const float*)d_in[4];
  const float* b2 = (const float*)d_in[5];
  const float* wc = (const float*)d_in[6];
  const float* bc = (const float*)d_in[7];
  const float* wb = (const float*)d_in[8];
  const float* bb = (const float*)d_in[9];

  const size_t XE = (size_t)NROI * K1;
  const size_t WE = (size_t)K1 * HID;
  const size_t FLOATS_TAIL =
      (size_t)ZSPLIT * NROI * HID + 2 * (size_t)NROI * HID + (size_t)NIMG * MCAND * 10;
  const size_t NEED = (XE * 2 + WE * 2) * sizeof(u16) + FLOATS_TAIL * sizeof(float);

  if (ws_size >= NEED) {
    u16* Xhi = (u16*)d_ws;
    u16* Xlo = Xhi + XE;
    u16* Wh  = Xlo + XE;
    u16* Wl  = Wh + WE;
    float* CP  = (float*)(Wl + WE);
    // CP region: 8 partials (33.5 MB); FC2's 4 partials (CP2) alias its head —
    // CP is dead after bias_relu_bf16, CP2 written only by the later FC2.
    float* CP2 = CP;
    float* H2  = CP + (size_t)ZSPLIT * NROI * HID;
    float* BX2 = H2 + (size_t)NROI * HID;
    float* NB2 = BX2 + (size_t)NIMG * MCAND * 4;
    float* LV2 = NB2 + (size_t)NIMG * MCAND * 4;
    float* ksg = LV2 + (size_t)NIMG * MCAND;
    int*   kig = (int*)(ksg + (size_t)NIMG * 20 * NDET);
    int*   cntg = kig + (size_t)NIMG * 20 * NDET;
    // H1 hi/lo alias the Xhi region (dead after FC1); W2t hi/lo alias Xlo.
    // Stream order guarantees safety: gemm1 reads X before these are written.
    u16* H1h = Xhi;
    u16* H1l = Xhi + (size_t)NROI * HID;
    u16* W2h = Xlo;
    u16* W2l = Xlo + (size_t)HID * HID;

    convw_kernel<K1><<<dim3(K1 / 64, HID / 64), 256, 0, stream>>>(w1, Wh, Wl);
    roi_kernel<true><<<NROI, 256, 0, stream>>>(features, proposals, nullptr, Xhi, Xlo);
    gemm_mfma_split<K1, KCHUNK, true><<<dim3(8, 8, ZSPLIT), 512, 0, stream>>>(
        Xhi, Xlo, Wh, Wl, CP);
    bias_relu_bf16_kernel<<<(NROI * HID) / 256, 256, 0, stream>>>(CP, b1, H1h, H1l);
    convw_kernel<HID><<<dim3(HID / 64, HID / 64), 256, 0, stream>>>(w2, W2h, W2l);
    gemm_mfma_split<HID, KCHUNK2, false><<<dim3(8, 8, ZSPLIT2), 512, 0, stream>>>(
        H1h, H1l, W2h, W2l, CP2);
    bias_relu2_kernel<<<(NROI * HID) / 256, 256, 0, stream>>>(CP2, b2, H2);
    heads_kernel<<<NROI, 128, 0, stream>>>(H2, wc, bc, wb, bb, proposals,
                                           BX2, NB2, LV2);
    nms_class_kernel<<<NIMG * 20, 64, 0, stream>>>(NB2, LV2, ksg, kig, cntg);
    nms_merge_kernel<<<NIMG, 1024, 0, stream>>>(ksg, kig, cntg, BX2,
                                                (float*)d_out);
  } else {
    float* ws = (float*)d_ws;
    float* X   = ws;
    float* CP  = X + XE;
    float* H1  = CP + (size_t)ZSPLIT * NROI * HID;
    float* H2  = H1 + (size_t)NROI * HID;
    float* BX2 = H2 + (size_t)NROI * HID;
    float* NB2 = BX2 + (size_t)NIMG * MCAND * 4;
    float* LV2 = NB2 + (size_t)NIMG * MCAND * 4;
    float* ksg = LV2 + (size_t)NIMG * MCAND;
    int*   kig = (int*)(ksg + (size_t)NIMG * 20 * NDET);
    int*   cntg = kig + (size_t)NIMG * 20 * NDET;

    roi_kernel<false><<<NROI, 256, 0, stream>>>(features, proposals, X, nullptr, nullptr);
    gemm1_kernel<<<dim3(16, 16, ZSPLIT), 256, 0, stream>>>(X, w1, CP);
    bias_relu_f32_kernel<<<(NROI * HID) / 256, 256, 0, stream>>>(CP, b1, H1);
    gemm2_kernel<<<dim3(16, 16), 256, 0, stream>>>(H1, w2, b2, H2);
    heads_kernel<<<NROI, 128, 0, stream>>>(H2, wc, bc, wb, bb, proposals,
                                           BX2, NB2, LV2);
    nms_class_kernel<<<NIMG * 20, 64, 0, stream>>>(NB2, LV2, ksg, kig, cntg);
    nms_merge_kernel<<<NIMG, 1024, 0, stream>>>(ksg, kig, cntg, BX2,
                                                (float*)d_out);
  }
}

// Round 3
// 835.371 us; speedup vs baseline: 1.0063x; 1.0063x over previous
//
#include <hip/hip_runtime.h>
#include <cmath>

// Problem constants (N=2, S=512, C=512, H=W=50, OUT=7, RATIO=2)
#define NIMG 2
#define SPROP 512
#define NROI 1024          // NIMG*SPROP
#define CCH 512
#define FH 50
#define FW 50
#define K1 25088           // CCH*7*7
#define HID 1024
#define NCLS 21
#define NDET 100
#define IMGSZ 800.0f
#define LOGMAX 4.135166556742356f   // log(1000/16)
#define MCAND 10240        // SPROP*(NCLS-1)
#define ZSPLIT 8
#define KCHUNK 3136        // K1/ZSPLIT
#define ZSPLIT2 8
#define KCHUNK2 128        // HID/ZSPLIT2

typedef unsigned short u16;
typedef __attribute__((ext_vector_type(8))) short short8;
typedef __attribute__((ext_vector_type(4))) float f32x4;
typedef __attribute__((ext_vector_type(16))) float f32x16;

__device__ __forceinline__ u16 f2bf(float x) {        // RTNE fp32 -> bf16
  unsigned int u = __float_as_uint(x);
  u += 0x7fffu + ((u >> 16) & 1u);
  return (u16)(u >> 16);
}
__device__ __forceinline__ float bf2f(u16 h) {
  return __uint_as_float(((unsigned int)h) << 16);
}

// ------------------------------------------------------------ ROI align
template <bool BF16OUT>
__global__ __launch_bounds__(256) void roi_kernel(
    const float* __restrict__ feat, const float* __restrict__ props,
    float* __restrict__ X, u16* __restrict__ Xhi, u16* __restrict__ Xlo) {
  const int r = blockIdx.x;
  const int n = r >> 9;
  const int tid = threadIdx.x;
  __shared__ float tile[32][256];   // 32 ch x (16x16 px) = 32 KB
  __shared__ int sy0[14], sy1[14], sx0[14], sx1[14];
  __shared__ float sly[14], slx[14], svy[14], svx[14];

  const float p0 = props[r * 4 + 0] * 0.0625f;
  const float p1 = props[r * 4 + 1] * 0.0625f;
  const float p2 = props[r * 4 + 2] * 0.0625f;
  const float p3 = props[r * 4 + 3] * 0.0625f;
  const float bw = fmaxf(p2 - p0, 1.0f) / 7.0f;
  const float bh = fmaxf(p3 - p1, 1.0f) / 7.0f;

  if (tid < 14) {
    const int j = tid;
    const float g = (float)(j >> 1) + ((float)(j & 1) + 0.5f) * 0.5f;
    float y = p1 + g * bh;
    svy[j] = (y > -1.0f && y < (float)FH) ? 1.0f : 0.0f;
    float yc = fminf(fmaxf(y, 0.0f), (float)(FH - 1));
    int y0 = (int)floorf(yc);
    sy0[j] = y0; sy1[j] = min(y0 + 1, FH - 1); sly[j] = yc - (float)y0;
    float x = p0 + g * bw;
    svx[j] = (x > -1.0f && x < (float)FW) ? 1.0f : 0.0f;
    float xc = fminf(fmaxf(x, 0.0f), (float)(FW - 1));
    int x0 = (int)floorf(xc);
    sx0[j] = x0; sx1[j] = min(x0 + 1, FW - 1); slx[j] = xc - (float)x0;
  }
  __syncthreads();
  const int ymin = sy0[0], xmin = sx0[0];
  const float* fb = feat + (size_t)n * CCH * (FH * FW);

  for (int cc = 0; cc < 16; ++cc) {
    const int c0 = cc * 32;
#pragma unroll
    for (int e = 0; e < 32; ++e) {
      const int idx = tid + e * 256;
      const int c = idx >> 8, p = idx & 255;
      const int gy = min(ymin + (p >> 4), FH - 1);
      const int gx = min(xmin + (p & 15), FW - 1);
      tile[c][p] = fb[(size_t)(c0 + c) * (FH * FW) + gy * FW + gx];
    }
    __syncthreads();
#pragma unroll
    for (int e = 0; e < 7; ++e) {
      const int idx = tid + e * 256;
      if (idx < 1568) {
        const int c = idx / 49;
        const int s = idx - c * 49;
        const int oy = s / 7, ox = s - (s / 7) * 7;
        float acc = 0.0f;
#pragma unroll
        for (int sy = 0; sy < 2; ++sy) {
          const int yj = oy * 2 + sy;
          const int py0 = sy0[yj] - ymin, py1 = sy1[yj] - ymin;
          const float ly = sly[yj], vy = svy[yj];
#pragma unroll
          for (int sx = 0; sx < 2; ++sx) {
            const int xj = ox * 2 + sx;
            const int px0 = sx0[xj] - xmin, px1 = sx1[xj] - xmin;
            const float lx = slx[xj], vx = svx[xj];
            const float f00 = tile[c][py0 * 16 + px0];
            const float f01 = tile[c][py0 * 16 + px1];
            const float f10 = tile[c][py1 * 16 + px0];
            const float f11 = tile[c][py1 * 16 + px1];
            float v = f00 * (1.0f - ly) * (1.0f - lx) + f01 * (1.0f - ly) * lx +
                      f10 * ly * (1.0f - lx) + f11 * ly * lx;
            acc += v * (vy * vx);
          }
        }
        const float v = acc * 0.25f;
        const size_t k = (size_t)r * K1 + (size_t)(c0 + c) * 49 + s;
        if (BF16OUT) {
          const u16 h = f2bf(v);
          Xhi[k] = h;
          Xlo[k] = f2bf(v - bf2f(h));
        } else {
          X[k] = v;
        }
      }
    }
    __syncthreads();
  }
}

// ------------------------- w -> hi/lo bf16, transposed to [n][k]
// Generic over K dimension (w1: K1 x HID, w2: HID x HID), both [k][n] in.
template <int KDIM>
__global__ __launch_bounds__(256) void convw_kernel(
    const float* __restrict__ w, u16* __restrict__ Wh, u16* __restrict__ Wl) {
  __shared__ u16 sh[64][65], sl[64][65];
  const int k0 = blockIdx.x * 64;
  const int n0 = blockIdx.y * 64;
  const int t = threadIdx.x;
#pragma unroll
  for (int e = 0; e < 16; ++e) {
    const int idx = t + e * 256;
    const int kl = idx >> 6, nl = idx & 63;
    const float v = w[(size_t)(k0 + kl) * HID + n0 + nl];
    const u16 h = f2bf(v);
    sh[kl][nl] = h;
    sl[kl][nl] = f2bf(v - bf2f(h));
  }
  __syncthreads();
#pragma unroll
  for (int e = 0; e < 16; ++e) {
    const int idx = t + e * 256;
    const int nl = idx >> 6, kl = idx & 63;
    Wh[(size_t)(n0 + nl) * KDIM + k0 + kl] = sh[kl][nl];
    Wl[(size_t)(n0 + nl) * KDIM + k0 + kl] = sl[kl][nl];
  }
}

// --------------- split-bf16 MFMA GEMM (32x32x16), generic K-stride / K-chunk
// Round-10: geometry fix from r9 post-mortem. r9 counters (MfmaUtil 40.7 flat,
// conflicts UP 1.5x, HBM/occupancy fixed) => kernel is LDS-BANDWIDTH bound.
// LDS reads per MFMA for split-bf16 with m x n wave tile = (2m+2n)/3mn:
// r9's 1x2 waves = 1.0 (worst); this round: 128x256 block, 8 waves of 64x64
// (2x2) = 0.67, grid stays 256 blocks (4,8,8). Aggregate LDS ops per CU-K-step
// drops 256 -> 176 per 384 MFMA-cycles.
//  * XCD swizzle (T1): z = flat%8 (one K-chunk slice per XCD L2). FETCH was
//    155 MB (< unique) in r9 — keep.
//  * LDS [rows][32] u16 + 16B-chunk XOR swizzle chunk' = chunk ^ ((row>>1)&3),
//    same involution on write & read.
//  * 2-deep register prefetch: ds_write of set A waits only set A's loads.
// A/B frag: [row = lane&31][k = (lane>>5)*8 + j].
// C/D: col = lane&31, row = (reg&3) + 8*(reg>>2) + 4*(lane>>5)  [m74/m101].
template <int KS, int KCH, bool SWZ>
__global__ __launch_bounds__(512, 2) void gemm_mfma_split(
    const u16* __restrict__ Ahg, const u16* __restrict__ Alg,
    const u16* __restrict__ Bhg, const u16* __restrict__ Blg,
    float* __restrict__ CP) {
  __shared__ u16 Ah[128][32], Al[128][32], Bh[256][32], Bl[256][32];
  const int tid = threadIdx.x;
  const int lane = tid & 63;
  const int wv = tid >> 6;           // 0..7
  const int wm = (wv >> 2) << 6;     // A row band {0,64}
  const int wn = (wv & 3) << 6;      // B col band {0,64,128,192}

  int bx = blockIdx.x, by = blockIdx.y, bz = blockIdx.z;
  if (SWZ) {
    // grid must be (4,8,8): XCD (= flat%8 under round-robin dispatch) <-> z.
    const int f = blockIdx.x + ((blockIdx.y + (blockIdx.z << 3)) << 2);
    bz = f & 7;
    const int u = f >> 3;            // 0..31
    bx = u & 3;
    by = u >> 2;
  }
  const int mT = by << 7;            // 128-row tiles
  const int nT = bx << 8;            // 256-col tiles
  const int kz = bz * KCH;
  const int kend = kz + KCH;

  // staging: A rows 0..127 (1 uint4/thread/array), B rows 0..255 (2/thread)
  const int sr = tid >> 2;                                  // 0..127
  const int sq = (tid & 3) << 3;                            // src col (u16)
  // swizzled dst col; rows r and r+128 share the same value ((128>>1)&3==0)
  const int scw = (((tid & 3) ^ ((sr >> 1) & 3)) << 3);
  const size_t aoff  = (size_t)(mT + sr) * KS + sq;
  const size_t b0off = (size_t)(nT + sr) * KS + sq;
  const size_t b1off = (size_t)(nT + sr + 128) * KS + sq;

  f32x16 acc[2][2];
#pragma unroll
  for (int i = 0; i < 2; ++i)
#pragma unroll
    for (int j = 0; j < 2; ++j)
#pragma unroll
      for (int e = 0; e < 16; ++e) acc[i][j][e] = 0.0f;

  const int fm = lane & 31;          // row within 32-tile
  const int fh = lane >> 5;          // k-subgroup (0/1)
  const int vswz = (fm >> 1) & 3;    // read-side swizzle (row-derived)

  // prologue: 2-deep staging (set R = k, set S = k+32), 6 uint4 each
  uint4 rA  = *(const uint4*)(Ahg + aoff + kz);
  uint4 rL  = *(const uint4*)(Alg + aoff + kz);
  uint4 rB0 = *(const uint4*)(Bhg + b0off + kz);
  uint4 rB1 = *(const uint4*)(Bhg + b1off + kz);
  uint4 rM0 = *(const uint4*)(Blg + b0off + kz);
  uint4 rM1 = *(const uint4*)(Blg + b1off + kz);
  uint4 sA  = *(const uint4*)(Ahg + aoff + kz + 32);
  uint4 sL  = *(const uint4*)(Alg + aoff + kz + 32);
  uint4 sB0 = *(const uint4*)(Bhg + b0off + kz + 32);
  uint4 sB1 = *(const uint4*)(Bhg + b1off + kz + 32);
  uint4 sM0 = *(const uint4*)(Blg + b0off + kz + 32);
  uint4 sM1 = *(const uint4*)(Blg + b1off + kz + 32);

  auto compute = [&]() {
#pragma unroll
    for (int kh = 0; kh < 2; ++kh) {
      const int cA = ((((kh << 1) | fh) ^ vswz) << 3);
      short8 fa_h[2], fa_l[2], fb_h[2], fb_l[2];
#pragma unroll
      for (int t = 0; t < 2; ++t) {
        fa_h[t] = *(const short8*)(&Ah[wm + t * 32 + fm][cA]);
        fa_l[t] = *(const short8*)(&Al[wm + t * 32 + fm][cA]);
        fb_h[t] = *(const short8*)(&Bh[wn + t * 32 + fm][cA]);
        fb_l[t] = *(const short8*)(&Bl[wn + t * 32 + fm][cA]);
      }
#pragma unroll
      for (int ti = 0; ti < 2; ++ti)
#pragma unroll
        for (int tj = 0; tj < 2; ++tj) {
          acc[ti][tj] = __builtin_amdgcn_mfma_f32_32x32x16_bf16(
              fa_h[ti], fb_h[tj], acc[ti][tj], 0, 0, 0);
          acc[ti][tj] = __builtin_amdgcn_mfma_f32_32x32x16_bf16(
              fa_h[ti], fb_l[tj], acc[ti][tj], 0, 0, 0);
          acc[ti][tj] = __builtin_amdgcn_mfma_f32_32x32x16_bf16(
              fa_l[ti], fb_h[tj], acc[ti][tj], 0, 0, 0);
        }
    }
  };

  for (int kb = kz; kb < kend; kb += 64) {
    // ---- half 1: consume set R (tile kb)
    *(uint4*)(&Ah[sr][scw]) = rA;     // waits only set-R loads (counted vmcnt)
    *(uint4*)(&Al[sr][scw]) = rL;
    *(uint4*)(&Bh[sr][scw]) = rB0;
    *(uint4*)(&Bh[sr + 128][scw]) = rB1;
    *(uint4*)(&Bl[sr][scw]) = rM0;
    *(uint4*)(&Bl[sr + 128][scw]) = rM1;
    __syncthreads();
    const int kn1 = (kb + 64 < kend) ? kb + 64 : kz;   // fallback: safe addr
    rA  = *(const uint4*)(Ahg + aoff + kn1);
    rL  = *(const uint4*)(Alg + aoff + kn1);
    rB0 = *(const uint4*)(Bhg + b0off + kn1);
    rB1 = *(const uint4*)(Bhg + b1off + kn1);
    rM0 = *(const uint4*)(Blg + b0off + kn1);
    rM1 = *(const uint4*)(Blg + b1off + kn1);
    compute();
    __syncthreads();
    // ---- half 2: consume set S (tile kb+32)
    *(uint4*)(&Ah[sr][scw]) = sA;
    *(uint4*)(&Al[sr][scw]) = sL;
    *(uint4*)(&Bh[sr][scw]) = sB0;
    *(uint4*)(&Bh[sr + 128][scw]) = sB1;
    *(uint4*)(&Bl[sr][scw]) = sM0;
    *(uint4*)(&Bl[sr + 128][scw]) = sM1;
    __syncthreads();
    const int kn2 = (kb + 96 < kend) ? kb + 96 : kz;
    sA  = *(const uint4*)(Ahg + aoff + kn2);
    sL  = *(const uint4*)(Alg + aoff + kn2);
    sB0 = *(const uint4*)(Bhg + b0off + kn2);
    sB1 = *(const uint4*)(Bhg + b1off + kn2);
    sM0 = *(const uint4*)(Blg + b0off + kn2);
    sM1 = *(const uint4*)(Blg + b1off + kn2);
    compute();
    __syncthreads();
  }

  float* Cp = CP + (size_t)bz * ((size_t)NROI * HID);   // bz: swizzled!
  const int ccol = nT + wn + fm;
  const int rbase = mT + wm + (fh << 2);
#pragma unroll
  for (int ti = 0; ti < 2; ++ti)
#pragma unroll
    for (int tj = 0; tj < 2; ++tj)
#pragma unroll
      for (int rg = 0; rg < 16; ++rg) {
        const int row = rbase + ti * 32 + (rg & 3) + 8 * (rg >> 2);
        Cp[(size_t)row * HID + ccol + tj * 32] = acc[ti][tj][rg];
      }
}

// ------------------------------------------------------- FC1 fallback (fp32)
__global__ __launch_bounds__(256) void gemm1_kernel(
    const float* __restrict__ A, const float* __restrict__ B,
    float* __restrict__ CP) {
  __shared__ float As[16][68];
  __shared__ float Bs[16][68];
  const int tid = threadIdx.x;
  const int mTile = blockIdx.y << 6;
  const int nTile = blockIdx.x << 6;
  const int k0 = blockIdx.z * KCHUNK;
  const int ty = tid >> 4, tx = tid & 15;
  const int ar = tid >> 2, ac = (tid & 3) << 2;
  const int br = tid >> 4, bcl = (tid & 15) << 2;
  float acc[4][4] = {};

  for (int kb = k0; kb < k0 + KCHUNK; kb += 16) {
    const float4 av = *(const float4*)(A + (size_t)(mTile + ar) * K1 + kb + ac);
    const float4 bv = *(const float4*)(B + (size_t)(kb + br) * HID + nTile + bcl);
    As[ac + 0][ar] = av.x; As[ac + 1][ar] = av.y;
    As[ac + 2][ar] = av.z; As[ac + 3][ar] = av.w;
    *(float4*)(&Bs[br][bcl]) = bv;
    __syncthreads();
#pragma unroll
    for (int kk = 0; kk < 16; ++kk) {
      const float4 a4 = *(const float4*)(&As[kk][ty << 2]);
      const float4 b4 = *(const float4*)(&Bs[kk][tx << 2]);
      const float aa[4] = {a4.x, a4.y, a4.z, a4.w};
      const float bb4[4] = {b4.x, b4.y, b4.z, b4.w};
#pragma unroll
      for (int i = 0; i < 4; ++i)
#pragma unroll
        for (int j = 0; j < 4; ++j)
          acc[i][j] = fmaf(aa[i], bb4[j], acc[i][j]);
    }
    __syncthreads();
  }
  float* Cp = CP + (size_t)blockIdx.z * (HID * NROI);
#pragma unroll
  for (int i = 0; i < 4; ++i) {
    *(float4*)(Cp + (size_t)(mTile + (ty << 2) + i) * HID + nTile + (tx << 2)) =
        make_float4(acc[i][0], acc[i][1], acc[i][2], acc[i][3]);
  }
}

// reduce 8 K-partials + bias + relu -> H1 as split-bf16 (feeds FC2 MFMA)
__global__ __launch_bounds__(256) void bias_relu_bf16_kernel(
    const float* __restrict__ CP, const float* __restrict__ b1,
    u16* __restrict__ H1h, u16* __restrict__ H1l) {
  const int idx = blockIdx.x * 256 + threadIdx.x;
  float v = b1[idx & (HID - 1)];
#pragma unroll
  for (int z = 0; z < ZSPLIT; ++z) v += CP[(size_t)z * (HID * NROI) + idx];
  v = fmaxf(v, 0.0f);
  const u16 h = f2bf(v);
  H1h[idx] = h;
  H1l[idx] = f2bf(v - bf2f(h));
}

// fp32 variant for the fallback path
__global__ __launch_bounds__(256) void bias_relu_f32_kernel(
    const float* __restrict__ CP, const float* __restrict__ b1,
    float* __restrict__ H1) {
  const int idx = blockIdx.x * 256 + threadIdx.x;
  float v = b1[idx & (HID - 1)];
#pragma unroll
  for (int z = 0; z < ZSPLIT; ++z) v += CP[(size_t)z * (HID * NROI) + idx];
  H1[idx] = fmaxf(v, 0.0f);
}

// reduce 8 K-partials of FC2 + bias + relu -> H2 fp32
__global__ __launch_bounds__(256) void bias_relu2_kernel(
    const float* __restrict__ CP2, const float* __restrict__ b2,
    float* __restrict__ H2) {
  const int idx = blockIdx.x * 256 + threadIdx.x;
  float v = b2[idx & (HID - 1)];
#pragma unroll
  for (int z = 0; z < ZSPLIT2; ++z) v += CP2[(size_t)z * (HID * NROI) + idx];
  H2[idx] = fmaxf(v, 0.0f);
}

// ------------------------------------------------------------- FC2 (K=1024)
// fp32 fallback only (bf16 path uses gemm_mfma_split<HID, KCHUNK2, true>)
__global__ __launch_bounds__(256) void gemm2_kernel(
    const float* __restrict__ A, const float* __restrict__ B,
    const float* __restrict__ bias, float* __restrict__ C) {
  __shared__ float As[16][68];
  __shared__ float Bs[16][68];
  const int tid = threadIdx.x;
  const int mTile = blockIdx.y << 6;
  const int nTile = blockIdx.x << 6;
  const int ty = tid >> 4, tx = tid & 15;
  const int ar = tid >> 2, ac = (tid & 3) << 2;
  const int br = tid >> 4, bcl = (tid & 15) << 2;
  float acc[4][4] = {};

  for (int kb = 0; kb < HID; kb += 16) {
    const float4 av = *(const float4*)(A + (size_t)(mTile + ar) * HID + kb + ac);
    const float4 bv = *(const float4*)(B + (size_t)(kb + br) * HID + nTile + bcl);
    As[ac + 0][ar] = av.x; As[ac + 1][ar] = av.y;
    As[ac + 2][ar] = av.z; As[ac + 3][ar] = av.w;
    *(float4*)(&Bs[br][bcl]) = bv;
    __syncthreads();
#pragma unroll
    for (int kk = 0; kk < 16; ++kk) {
      const float4 a4 = *(const float4*)(&As[kk][ty << 2]);
      const float4 b4 = *(const float4*)(&Bs[kk][tx << 2]);
      const float aa[4] = {a4.x, a4.y, a4.z, a4.w};
      const float bb4[4] = {b4.x, b4.y, b4.z, b4.w};
#pragma unroll
      for (int i = 0; i < 4; ++i)
#pragma unroll
        for (int j = 0; j < 4; ++j)
          acc[i][j] = fmaf(aa[i], bb4[j], acc[i][j]);
    }
    __syncthreads();
  }
#pragma unroll
  for (int i = 0; i < 4; ++i) {
#pragma unroll
    for (int j = 0; j < 4; ++j) {
      float v = acc[i][j] + bias[nTile + (tx << 2) + j];
      acc[i][j] = fmaxf(v, 0.0f);
    }
    *(float4*)(C + (size_t)(mTile + (ty << 2) + i) * HID + nTile + (tx << 2)) =
        make_float4(acc[i][0], acc[i][1], acc[i][2], acc[i][3]);
  }
}

// ------------------- heads: cls+box dots, softmax, decode, candidate arrays
// Candidate layout is CLASS-MAJOR: index = n*MCAND + (k-1)*SPROP + s
__global__ __launch_bounds__(128) void heads_kernel(
    const float* __restrict__ H2m, const float* __restrict__ wc,
    const float* __restrict__ bc, const float* __restrict__ wb,
    const float* __restrict__ bb, const float* __restrict__ props,
    float* __restrict__ BX2, float* __restrict__ NB2,
    float* __restrict__ LV2) {
  const int r = blockIdx.x;
  const int tid = threadIdx.x;
  __shared__ float hrow[HID];
  __shared__ float vals[112];
  __shared__ float red[2];

  for (int i = tid; i < HID; i += 128) hrow[i] = H2m[(size_t)r * HID + i];
  __syncthreads();

  if (tid < 105) {
    float acc;
    if (tid < NCLS) {
      acc = bc[tid];
      for (int kk = 0; kk < HID; ++kk) acc = fmaf(hrow[kk], wc[kk * NCLS + tid], acc);
    } else {
      const int j = tid - NCLS;
      acc = bb[j];
      for (int kk = 0; kk < HID; ++kk) acc = fmaf(hrow[kk], wb[kk * (NCLS * 4) + j], acc);
    }
    vals[tid] = acc;
  }
  __syncthreads();

  if (tid == 0) {
    float m = vals[0];
    for (int k = 1; k < NCLS; ++k) m = fmaxf(m, vals[k]);
    float s = 0.0f;
    for (int k = 0; k < NCLS; ++k) s += expf(vals[k] - m);
    red[0] = m;
    red[1] = 1.0f / s;
  }
  __syncthreads();

  if (tid >= 1 && tid <= 20) {
    const int k = tid;
    const float prob = expf(vals[k] - red[0]) * red[1];

    const float px1 = props[r * 4 + 0], py1 = props[r * 4 + 1];
    const float px2 = props[r * 4 + 2], py2 = props[r * 4 + 3];
    const float pw = px2 - px1, ph = py2 - py1;
    const float pcx = px1 + 0.5f * pw, pcy = py1 + 0.5f * ph;

    const float dx = vals[NCLS + k * 4 + 0] / 10.0f;
    const float dy = vals[NCLS + k * 4 + 1] / 10.0f;
    const float dw = fminf(vals[NCLS + k * 4 + 2] / 5.0f, LOGMAX);
    const float dh = fminf(vals[NCLS + k * 4 + 3] / 5.0f, LOGMAX);

    const float cx = dx * pw + pcx, cy = dy * ph + pcy;
    const float w = expf(dw) * pw, h = expf(dh) * ph;
    float b0 = cx - 0.5f * w, b1c = cy - 0.5f * h;
    float b2 = cx + 0.5f * w, b3 = cy + 0.5f * h;
    b0 = fminf(fmaxf(b0, 0.0f), IMGSZ);
    b1c = fminf(fmaxf(b1c, 0.0f), IMGSZ);
    b2 = fminf(fmaxf(b2, 0.0f), IMGSZ);
    b3 = fminf(fmaxf(b3, 0.0f), IMGSZ);

    const float wv = b2 - b0, hv = b3 - b1c;
    const bool valid = (prob > 0.05f) && (wv >= 0.01f) && (hv >= 0.01f);

    const int n = r >> 9, s = r & 511;
    const int cand = (k - 1) * SPROP + s;     // class-major
    const size_t bi = (size_t)n * MCAND + cand;
    const float off = (float)k * (IMGSZ + 1.0f);

    BX2[bi * 4 + 0] = b0; BX2[bi * 4 + 1] = b1c;
    BX2[bi * 4 + 2] = b2; BX2[bi * 4 + 3] = b3;
    NB2[bi * 4 + 0] = b0 + off; NB2[bi * 4 + 1] = b1c + off;
    NB2[bi * 4 + 2] = b2 + off; NB2[bi * 4 + 3] = b3 + off;
    LV2[bi] = valid ? prob : -1.0f;
  }
}

// ---------------------------------------------- per-(image,class) greedy NMS
// Cross-class IoU == 0 (801*k offsets), so the global greedy restricted to a
// class equals the standalone per-class greedy (proved by induction on picks).
// One wave per (n,c): 512 slots in registers, barrier-free serial loop.
template <int CTRL>
__device__ __forceinline__ void red2(float& v, int& ix) {
  const float tv = __int_as_float(__builtin_amdgcn_update_dpp(
      (int)0xC0000000, __float_as_int(v), CTRL, 0xf, 0xf, false));
  const int ti = __builtin_amdgcn_update_dpp(0x7fffffff, ix, CTRL, 0xf, 0xf, false);
  if (tv > v || (tv == v && ti < ix)) { v = tv; ix = ti; }
}
__device__ __forceinline__ void wave_red2(float& v, int& ix) {
  red2<0x111>(v, ix);  // row_shr:1
  red2<0x112>(v, ix);  // row_shr:2
  red2<0x114>(v, ix);  // row_shr:4
  red2<0x118>(v, ix);  // row_shr:8
  red2<0x142>(v, ix);  // row_bcast:15
  red2<0x143>(v, ix);  // row_bcast:31 -> lane 63 holds winner
}

__global__ __launch_bounds__(64) void nms_class_kernel(
    const float* __restrict__ NB2, const float* __restrict__ LV2,
    float* __restrict__ ksg, int* __restrict__ kig, int* __restrict__ cntg) {
  const int bid = blockIdx.x;           // n*20 + c
  const int lane = threadIdx.x;         // 0..63
  __shared__ float4 lbox[SPROP];        // winner-broadcast copy
  const size_t cb = (size_t)bid * SPROP;

  float lv[8], b0[8], b1[8], b2[8], b3[8], ar[8];
#pragma unroll
  for (int j = 0; j < 8; ++j) {
    const int s = lane + j * 64;
    lv[j] = LV2[cb + s];
    const float4 b = *(const float4*)(NB2 + (cb + s) * 4);
    b0[j] = b.x; b1[j] = b.y; b2[j] = b.z; b3[j] = b.w;
    ar[j] = (b.z - b.x) * (b.w - b.y);
    lbox[s] = b;
  }

  int cnt = 0;
  for (int d = 0; d < NDET; ++d) {
    float bv = -2.0f;
    int bix = 0x7fffffff;
#pragma unroll
    for (int j = 0; j < 8; ++j) {     // j asc => slot asc; strict > keeps lowest
      if (lv[j] > bv) { bv = lv[j]; bix = lane + j * 64; }
    }
    wave_red2(bv, bix);
    const float bv2 = __shfl(bv, 63);
    const int bix2 = __shfl(bix, 63);
    if (bv2 <= 0.05f) break;          // all remaining dead; wave-uniform

    if (lane == 0) {
      ksg[bid * NDET + cnt] = bv2;
      kig[bid * NDET + cnt] = bix2;   // slot within class (0..511)
    }
    ++cnt;

    const float4 wb = lbox[bix2];     // same-wave LDS write->read, waitcnt ok
    const float wa = (wb.z - wb.x) * (wb.w - wb.y);
#pragma unroll
    for (int j = 0; j < 8; ++j) {
      const float xx1 = fmaxf(wb.x, b0[j]);
      const float yy1 = fmaxf(wb.y, b1[j]);
      const float xx2 = fminf(wb.z, b2[j]);
      const float yy2 = fminf(wb.w, b3[j]);
      const float inter = fmaxf(xx2 - xx1, 0.0f) * fmaxf(yy2 - yy1, 0.0f);
      const float iou = inter / (wa + ar[j] - inter + 1e-9f);
      if (iou > 0.5f) lv[j] = -1.0f;
    }
  }
  if (lane == 0) cntg[bid] = cnt;
}

// ------------------------------- merge: top-100 by (score desc, flat-idx asc)
// Global greedy order == keeps sorted by packed priority (scores non-increasing
// along greedy; tied keeps are simultaneously live so argmax first-index rule
// = lowest flat idx). Rank-based selection: zero barriers in the hot loop.
__global__ __launch_bounds__(1024) void nms_merge_kernel(
    const float* __restrict__ ksg, const int* __restrict__ kig,
    const int* __restrict__ cntg, const float* __restrict__ BX2,
    float* __restrict__ out) {
  const int n = blockIdx.x;
  const int tid = threadIdx.x;
  __shared__ int cbase[21];
  __shared__ unsigned long long keys[2000];
  __shared__ float ssc[2000];
  __shared__ int sfl[2000];
  __shared__ float svals[NDET];
  __shared__ int sflat[NDET];

  if (tid == 0) {
    int acc = 0;
    for (int c = 0; c < 20; ++c) { cbase[c] = acc; acc += cntg[n * 20 + c]; }
    cbase[20] = acc;
  }
  __syncthreads();
  const int T = cbase[20];     // <= 2000

  for (int idx = tid; idx < 20 * NDET; idx += 1024) {
    const int c = idx / NDET, e = idx - (idx / NDET) * NDET;
    if (e < cntg[n * 20 + c]) {
      const int pos = cbase[c] + e;
      const float s = ksg[(n * 20 + c) * NDET + e];
      const int slot = kig[(n * 20 + c) * NDET + e];
      const int flat = slot * 20 + c;            // original flat candidate idx
      ssc[pos] = s;
      sfl[pos] = flat;
      keys[pos] = ((unsigned long long)__float_as_uint(s) << 32) |
                  (unsigned long long)(0xFFFFFFFFu - (unsigned)flat);
    }
  }
  __syncthreads();

  float msc[2]; int mfl[2]; unsigned long long mk[2]; int rank[2] = {0, 0};
  bool own[2];
#pragma unroll
  for (int e = 0; e < 2; ++e) {
    const int i = tid + e * 1024;
    own[e] = (i < T);
    if (own[e]) { mk[e] = keys[i]; msc[e] = ssc[i]; mfl[e] = sfl[i]; }
  }
  for (int i = 0; i < T; ++i) {        // LDS broadcast read per iteration
    const unsigned long long k = keys[i];
    if (own[0] && k > mk[0]) ++rank[0];
    if (own[1] && k > mk[1]) ++rank[1];
  }
#pragma unroll
  for (int e = 0; e < 2; ++e)
    if (own[e] && rank[e] < NDET) { svals[rank[e]] = msc[e]; sflat[rank[e]] = mfl[e]; }
  __syncthreads();

  if (tid < NDET) {
    const int m = (T < NDET) ? T : NDET;
    const bool keep = tid < m;
    float sv = 0.0f;
    float4 bx4 = make_float4(0.0f, 0.0f, 0.0f, 0.0f);
    float label = 0.0f;
    if (keep) {
      sv = svals[tid];
      const int flat = sflat[tid];
      const int c = flat % 20, s = flat / 20;
      bx4 = *(const float4*)(BX2 + ((size_t)(n * 20 + c) * SPROP + s) * 4);
      label = (float)(c + 1);
    }
    out[(n * NDET + tid) * 4 + 0] = bx4.x;
    out[(n * NDET + tid) * 4 + 1] = bx4.y;
    out[(n * NDET + tid) * 4 + 2] = bx4.z;
    out[(n * NDET + tid) * 4 + 3] = bx4.w;
    out[NIMG * NDET * 4 + n * NDET + tid] = sv;
    out[NIMG * NDET * 4 + NIMG * NDET + n * NDET + tid] = label;
  }
}

// ---------------------------------------------------------------- launcher
extern "C" void kernel_launch(void* const* d_in, const int* in_sizes, int n_in,
                              void* d_out, int out_size, void* d_ws, size_t ws_size,
                              hipStream_t stream) {
  const float* features  = (const float*)d_in[0];
  const float* proposals = (const float*)d_in[1];
  const float* w1 = (const float*)d_in[2];
  const float* b1 = (const float*)d_in[3];
  const float* w2 = (const float*)d_in[4];
  const float* b2 = (const float*)d_in[5];
  const float* wc = (const float*)d_in[6];
  const float* bc = (const float*)d_in[7];
  const float* wb = (const float*)d_in[8];
  const float* bb = (const float*)d_in[9];

  const size_t XE = (size_t)NROI * K1;
  const size_t WE = (size_t)K1 * HID;
  const size_t FLOATS_TAIL =
      (size_t)ZSPLIT * NROI * HID + 2 * (size_t)NROI * HID + (size_t)NIMG * MCAND * 10;
  const size_t NEED = (XE * 2 + WE * 2) * sizeof(u16) + FLOATS_TAIL * sizeof(float);

  if (ws_size >= NEED) {
    u16* Xhi = (u16*)d_ws;
    u16* Xlo = Xhi + XE;
    u16* Wh  = Xlo + XE;
    u16* Wl  = Wh + WE;
    float* CP  = (float*)(Wl + WE);
    // CP region: 8 partials (33.5 MB); FC2's 8 partials (CP2) alias it —
    // CP is dead after bias_relu_bf16, CP2 written only by the later FC2.
    float* CP2 = CP;
    float* H2  = CP + (size_t)ZSPLIT * NROI * HID;
    float* BX2 = H2 + (size_t)NROI * HID;
    float* NB2 = BX2 + (size_t)NIMG * MCAND * 4;
    float* LV2 = NB2 + (size_t)NIMG * MCAND * 4;
    float* ksg = LV2 + (size_t)NIMG * MCAND;
    int*   kig = (int*)(ksg + (size_t)NIMG * 20 * NDET);
    int*   cntg = kig + (size_t)NIMG * 20 * NDET;
    // H1 hi/lo alias the Xhi region (dead after FC1); W2t hi/lo alias Xlo.
    // Stream order guarantees safety: gemm1 reads X before these are written.
    u16* H1h = Xhi;
    u16* H1l = Xhi + (size_t)NROI * HID;
    u16* W2h = Xlo;
    u16* W2l = Xlo + (size_t)HID * HID;

    convw_kernel<K1><<<dim3(K1 / 64, HID / 64), 256, 0, stream>>>(w1, Wh, Wl);
    roi_kernel<true><<<NROI, 256, 0, stream>>>(features, proposals, nullptr, Xhi, Xlo);
    gemm_mfma_split<K1, KCHUNK, true><<<dim3(4, 8, ZSPLIT), 512, 0, stream>>>(
        Xhi, Xlo, Wh, Wl, CP);
    bias_relu_bf16_kernel<<<(NROI * HID) / 256, 256, 0, stream>>>(CP, b1, H1h, H1l);
    convw_kernel<HID><<<dim3(HID / 64, HID / 64), 256, 0, stream>>>(w2, W2h, W2l);
    gemm_mfma_split<HID, KCHUNK2, true><<<dim3(4, 8, ZSPLIT2), 512, 0, stream>>>(
        H1h, H1l, W2h, W2l, CP2);
    bias_relu2_kernel<<<(NROI * HID) / 256, 256, 0, stream>>>(CP2, b2, H2);
    heads_kernel<<<NROI, 128, 0, stream>>>(H2, wc, bc, wb, bb, proposals,
                                           BX2, NB2, LV2);
    nms_class_kernel<<<NIMG * 20, 64, 0, stream>>>(NB2, LV2, ksg, kig, cntg);
    nms_merge_kernel<<<NIMG, 1024, 0, stream>>>(ksg, kig, cntg, BX2,
                                                (float*)d_out);
  } else {
    float* ws = (float*)d_ws;
    float* X   = ws;
    float* CP  = X + XE;
    float* H1  = CP + (size_t)ZSPLIT * NROI * HID;
    float* H2  = H1 + (size_t)NROI * HID;
    float* BX2 = H2 + (size_t)NROI * HID;
    float* NB2 = BX2 + (size_t)NIMG * MCAND * 4;
    float* LV2 = NB2 + (size_t)NIMG * MCAND * 4;
    float* ksg = LV2 + (size_t)NIMG * MCAND;
    int*   kig = (int*)(ksg + (size_t)NIMG * 20 * NDET);
    int*   cntg = kig + (size_t)NIMG * 20 * NDET;

    roi_kernel<false><<<NROI, 256, 0, stream>>>(features, proposals, X, nullptr, nullptr);
    gemm1_kernel<<<dim3(16, 16, ZSPLIT), 256, 0, stream>>>(X, w1, CP);
    bias_relu_f32_kernel<<<(NROI * HID) / 256, 256, 0, stream>>>(CP, b1, H1);
    gemm2_kernel<<<dim3(16, 16), 256, 0, stream>>>(H1, w2, b2, H2);
    heads_kernel<<<NROI, 128, 0, stream>>>(H2, wc, bc, wb, bb, proposals,
                                           BX2, NB2, LV2);
    nms_class_kernel<<<NIMG * 20, 64, 0, stream>>>(NB2, LV2, ksg, kig, cntg);
    nms_merge_kernel<<<NIMG, 1024, 0, stream>>>(ksg, kig, cntg, BX2,
                                                (float*)d_out);
  }
}

// Round 4
// 792.922 us; speedup vs baseline: 1.0601x; 1.0535x over previous
//
#include <hip/hip_runtime.h>
#include <cmath>

// Problem constants (N=2, S=512, C=512, H=W=50, OUT=7, RATIO=2)
#define NIMG 2
#define SPROP 512
#define NROI 1024          // NIMG*SPROP
#define CCH 512
#define FH 50
#define FW 50
#define K1 25088           // CCH*7*7
#define HID 1024
#define NCLS 21
#define NDET 100
#define IMGSZ 800.0f
#define LOGMAX 4.135166556742356f   // log(1000/16)
#define MCAND 10240        // SPROP*(NCLS-1)
#define ZSPLIT 8
#define KCHUNK 3136        // K1/ZSPLIT
#define ZSPLIT2 8
#define KCHUNK2 128        // HID/ZSPLIT2

typedef unsigned short u16;
typedef __attribute__((ext_vector_type(8))) short short8;
typedef __attribute__((ext_vector_type(4))) float f32x4;
typedef __attribute__((ext_vector_type(16))) float f32x16;

__device__ __forceinline__ u16 f2bf(float x) {        // RTNE fp32 -> bf16
  unsigned int u = __float_as_uint(x);
  u += 0x7fffu + ((u >> 16) & 1u);
  return (u16)(u >> 16);
}
__device__ __forceinline__ float bf2f(u16 h) {
  return __uint_as_float(((unsigned int)h) << 16);
}

// ------------------------------------------------------------ ROI align
// Round-11 rewrite from r3 counters (roi = new #1 at 187us: VALUBusy 36%,
// HBM 9.6%, MFMA 0, conflicts 20.6M -> LDS-ISSUE bound, ~48 lane-LDS-ops per
// output). Changes:
//  * weights factorize per-axis (masks included) -> per-sample float4 meta
//    {rowoff0, rowoff1, wy0, wy1} / {px0, wxa, wxb, -}: 4 b128 meta reads per
//    output instead of 32 scalar reads. x-clamp select folds into wxa/wxb
//    (dead neighbor read lands in pad column and is multiplied by 0; px0<=13
//    guaranteed since box span <= 12.25 feature px, so px0+1 is real data).
//  * f00/f01 pair-read (px0, px0+1 adjacent; row stride 17 pad) -> ds_read2.
//    Per output: 12 LDS instrs (was ~48).
//  * conflict-free layout: flat tile, channel stride 273 (odd), row stride 17;
//    lane map c=tid>>3 -> 17c distinct banks mod 32. No div-by-49 in hot loop.
//  * register prefetch of next 32-ch slab (32 VGPR) under compute phase.
template <bool BF16OUT>
__global__ __launch_bounds__(256) void roi_kernel(
    const float* __restrict__ feat, const float* __restrict__ props,
    float* __restrict__ X, u16* __restrict__ Xhi, u16* __restrict__ Xlo) {
  const int r = blockIdx.x;
  const int n = r >> 9;
  const int tid = threadIdx.x;
  __shared__ float tile[32 * 273 + 16];   // 32 ch x (16x17 px) +pad, ~35 KB
  __shared__ float4 ymeta[14];  // {asf(rowoff0), asf(rowoff1), wy0, wy1}
  __shared__ float4 xmeta[14];  // {asf(px0), wxa, wxb, 0}
  __shared__ int smin[2];       // ymin, xmin

  const float p0 = props[r * 4 + 0] * 0.0625f;
  const float p1 = props[r * 4 + 1] * 0.0625f;
  const float p2 = props[r * 4 + 2] * 0.0625f;
  const float p3 = props[r * 4 + 3] * 0.0625f;
  const float bw = fmaxf(p2 - p0, 1.0f) / 7.0f;
  const float bh = fmaxf(p3 - p1, 1.0f) / 7.0f;

  if (tid < 14) {               // y-axis metadata
    const int j = tid;
    const float g = (float)(j >> 1) + ((float)(j & 1) + 0.5f) * 0.5f;
    const float y = p1 + g * bh;
    const float vy = (y > -1.0f && y < (float)FH) ? 0.5f : 0.0f;  // fold 0.5
    const float yc = fminf(fmaxf(y, 0.0f), (float)(FH - 1));
    const int y0 = (int)floorf(yc);
    const int y1 = min(y0 + 1, FH - 1);
    const float ly = yc - (float)y0;
    // ymin recomputed identically per thread (sample j=0, g=0.25)
    const float yc0 = fminf(fmaxf(p1 + 0.25f * bh, 0.0f), (float)(FH - 1));
    const int ymin = (int)floorf(yc0);
    float4 m;
    m.x = __int_as_float((y0 - ymin) * 17);
    m.y = __int_as_float((y1 - ymin) * 17);
    m.z = (1.0f - ly) * vy;
    m.w = ly * vy;
    ymeta[j] = m;
    if (j == 0) smin[0] = ymin;
  } else if (tid >= 16 && tid < 30) {   // x-axis metadata
    const int j = tid - 16;
    const float g = (float)(j >> 1) + ((float)(j & 1) + 0.5f) * 0.5f;
    const float x = p0 + g * bw;
    const float vx = (x > -1.0f && x < (float)FW) ? 0.5f : 0.0f;
    const float xc = fminf(fmaxf(x, 0.0f), (float)(FW - 1));
    const int x0 = (int)floorf(xc);
    const int x1 = min(x0 + 1, FW - 1);
    const float lx = xc - (float)x0;
    const float xc0 = fminf(fmaxf(p0 + 0.25f * bw, 0.0f), (float)(FW - 1));
    const int xmin = (int)floorf(xc0);
    const float wx0 = (1.0f - lx) * vx;
    const float wx1 = lx * vx;
    const int d = x1 - x0;      // 0 or 1
    float4 m;
    m.x = __int_as_float(x0 - xmin);
    m.y = wx0 + (d ? 0.0f : wx1);   // wxa
    m.z = d ? wx1 : 0.0f;           // wxb
    m.w = 0.0f;
    xmeta[j] = m;
    if (j == 0) smin[1] = xmin;
  }
  __syncthreads();

  const int ymin = smin[0], xmin = smin[1];
  const float* fb = feat + (size_t)n * CCH * (FH * FW);
  // staging: thread owns pixel p = tid (16x16), channel = e
  const int gy = min(ymin + (tid >> 4), FH - 1);
  const int gx = min(xmin + (tid & 15), FW - 1);
  const int offp = gy * FW + gx;
  const int wslot = (tid >> 4) * 17 + (tid & 15);
  const int q = tid & 7;        // output-slot group
  const int c = tid >> 3;       // channel within slab (0..31)
  const int cb = c * 273;

  float pf[32];
#pragma unroll
  for (int e = 0; e < 32; ++e) pf[e] = fb[(size_t)e * (FH * FW) + offp];

  for (int cc = 0; cc < 16; ++cc) {
#pragma unroll
    for (int e = 0; e < 32; ++e) tile[e * 273 + wslot] = pf[e];
    __syncthreads();
    if (cc < 15) {
      const float* fb2 = fb + (size_t)(cc + 1) * 32 * (FH * FW);
#pragma unroll
      for (int e = 0; e < 32; ++e) pf[e] = fb2[(size_t)e * (FH * FW) + offp];
    }
#pragma unroll
    for (int jj = 0; jj < 7; ++jj) {
      const int s = q + (jj << 3);
      if (s < 49) {
        const int oy = s / 7;
        const int ox = s - oy * 7;
        const float4 ym0 = ymeta[2 * oy];
        const float4 ym1 = ymeta[2 * oy + 1];
        const float4 xm0 = xmeta[2 * ox];
        const float4 xm1 = xmeta[2 * ox + 1];
        float acc = 0.0f;
#pragma unroll
        for (int sy = 0; sy < 2; ++sy) {
          const float4 ym = sy ? ym1 : ym0;
          const int ro0 = cb + __float_as_int(ym.x);
          const int ro1 = cb + __float_as_int(ym.y);
#pragma unroll
          for (int sx = 0; sx < 2; ++sx) {
            const float4 xm = sx ? xm1 : xm0;
            const int px = __float_as_int(xm.x);
            const float a0 = tile[ro0 + px];
            const float a1 = tile[ro0 + px + 1];
            const float b0 = tile[ro1 + px];
            const float b1 = tile[ro1 + px + 1];
            acc += ym.z * (xm.y * a0 + xm.z * a1) +
                   ym.w * (xm.y * b0 + xm.z * b1);
          }
        }
        const size_t k = (size_t)r * K1 + (size_t)(cc * 32 + c) * 49 + s;
        if (BF16OUT) {
          const u16 h = f2bf(acc);
          Xhi[k] = h;
          Xlo[k] = f2bf(acc - bf2f(h));
        } else {
          X[k] = acc;
        }
      }
    }
    __syncthreads();
  }
}

// ------------------------- w -> hi/lo bf16, transposed to [n][k]
// Generic over K dimension (w1: K1 x HID, w2: HID x HID), both [k][n] in.
template <int KDIM>
__global__ __launch_bounds__(256) void convw_kernel(
    const float* __restrict__ w, u16* __restrict__ Wh, u16* __restrict__ Wl) {
  __shared__ u16 sh[64][65], sl[64][65];
  const int k0 = blockIdx.x * 64;
  const int n0 = blockIdx.y * 64;
  const int t = threadIdx.x;
#pragma unroll
  for (int e = 0; e < 16; ++e) {
    const int idx = t + e * 256;
    const int kl = idx >> 6, nl = idx & 63;
    const float v = w[(size_t)(k0 + kl) * HID + n0 + nl];
    const u16 h = f2bf(v);
    sh[kl][nl] = h;
    sl[kl][nl] = f2bf(v - bf2f(h));
  }
  __syncthreads();
#pragma unroll
  for (int e = 0; e < 16; ++e) {
    const int idx = t + e * 256;
    const int nl = idx >> 6, kl = idx & 63;
    Wh[(size_t)(n0 + nl) * KDIM + k0 + kl] = sh[kl][nl];
    Wl[(size_t)(n0 + nl) * KDIM + k0 + kl] = sl[kl][nl];
  }
}

// --------------- split-bf16 MFMA GEMM (32x32x16), generic K-stride / K-chunk
// r10 geometry: 128x256 tile, 8 waves of 64x64 (2x2), LDS-read:MFMA = 0.67.
// XCD swizzle (T1): z = flat%8. LDS [rows][32] u16 + 16B-chunk XOR swizzle.
// 2-deep register prefetch. A/B frag: [row = lane&31][k = (lane>>5)*8 + j].
// C/D: col = lane&31, row = (reg&3) + 8*(reg>>2) + 4*(lane>>5)  [m74/m101].
template <int KS, int KCH, bool SWZ>
__global__ __launch_bounds__(512, 2) void gemm_mfma_split(
    const u16* __restrict__ Ahg, const u16* __restrict__ Alg,
    const u16* __restrict__ Bhg, const u16* __restrict__ Blg,
    float* __restrict__ CP) {
  __shared__ u16 Ah[128][32], Al[128][32], Bh[256][32], Bl[256][32];
  const int tid = threadIdx.x;
  const int lane = tid & 63;
  const int wv = tid >> 6;           // 0..7
  const int wm = (wv >> 2) << 6;     // A row band {0,64}
  const int wn = (wv & 3) << 6;      // B col band {0,64,128,192}

  int bx = blockIdx.x, by = blockIdx.y, bz = blockIdx.z;
  if (SWZ) {
    // grid must be (4,8,8): XCD (= flat%8 under round-robin dispatch) <-> z.
    const int f = blockIdx.x + ((blockIdx.y + (blockIdx.z << 3)) << 2);
    bz = f & 7;
    const int u = f >> 3;            // 0..31
    bx = u & 3;
    by = u >> 2;
  }
  const int mT = by << 7;            // 128-row tiles
  const int nT = bx << 8;            // 256-col tiles
  const int kz = bz * KCH;
  const int kend = kz + KCH;

  // staging: A rows 0..127 (1 uint4/thread/array), B rows 0..255 (2/thread)
  const int sr = tid >> 2;                                  // 0..127
  const int sq = (tid & 3) << 3;                            // src col (u16)
  // swizzled dst col; rows r and r+128 share the same value ((128>>1)&3==0)
  const int scw = (((tid & 3) ^ ((sr >> 1) & 3)) << 3);
  const size_t aoff  = (size_t)(mT + sr) * KS + sq;
  const size_t b0off = (size_t)(nT + sr) * KS + sq;
  const size_t b1off = (size_t)(nT + sr + 128) * KS + sq;

  f32x16 acc[2][2];
#pragma unroll
  for (int i = 0; i < 2; ++i)
#pragma unroll
    for (int j = 0; j < 2; ++j)
#pragma unroll
      for (int e = 0; e < 16; ++e) acc[i][j][e] = 0.0f;

  const int fm = lane & 31;          // row within 32-tile
  const int fh = lane >> 5;          // k-subgroup (0/1)
  const int vswz = (fm >> 1) & 3;    // read-side swizzle (row-derived)

  // prologue: 2-deep staging (set R = k, set S = k+32), 6 uint4 each
  uint4 rA  = *(const uint4*)(Ahg + aoff + kz);
  uint4 rL  = *(const uint4*)(Alg + aoff + kz);
  uint4 rB0 = *(const uint4*)(Bhg + b0off + kz);
  uint4 rB1 = *(const uint4*)(Bhg + b1off + kz);
  uint4 rM0 = *(const uint4*)(Blg + b0off + kz);
  uint4 rM1 = *(const uint4*)(Blg + b1off + kz);
  uint4 sA  = *(const uint4*)(Ahg + aoff + kz + 32);
  uint4 sL  = *(const uint4*)(Alg + aoff + kz + 32);
  uint4 sB0 = *(const uint4*)(Bhg + b0off + kz + 32);
  uint4 sB1 = *(const uint4*)(Bhg + b1off + kz + 32);
  uint4 sM0 = *(const uint4*)(Blg + b0off + kz + 32);
  uint4 sM1 = *(const uint4*)(Blg + b1off + kz + 32);

  auto compute = [&]() {
#pragma unroll
    for (int kh = 0; kh < 2; ++kh) {
      const int cA = ((((kh << 1) | fh) ^ vswz) << 3);
      short8 fa_h[2], fa_l[2], fb_h[2], fb_l[2];
#pragma unroll
      for (int t = 0; t < 2; ++t) {
        fa_h[t] = *(const short8*)(&Ah[wm + t * 32 + fm][cA]);
        fa_l[t] = *(const short8*)(&Al[wm + t * 32 + fm][cA]);
        fb_h[t] = *(const short8*)(&Bh[wn + t * 32 + fm][cA]);
        fb_l[t] = *(const short8*)(&Bl[wn + t * 32 + fm][cA]);
      }
#pragma unroll
      for (int ti = 0; ti < 2; ++ti)
#pragma unroll
        for (int tj = 0; tj < 2; ++tj) {
          acc[ti][tj] = __builtin_amdgcn_mfma_f32_32x32x16_bf16(
              fa_h[ti], fb_h[tj], acc[ti][tj], 0, 0, 0);
          acc[ti][tj] = __builtin_amdgcn_mfma_f32_32x32x16_bf16(
              fa_h[ti], fb_l[tj], acc[ti][tj], 0, 0, 0);
          acc[ti][tj] = __builtin_amdgcn_mfma_f32_32x32x16_bf16(
              fa_l[ti], fb_h[tj], acc[ti][tj], 0, 0, 0);
        }
    }
  };

  for (int kb = kz; kb < kend; kb += 64) {
    // ---- half 1: consume set R (tile kb)
    *(uint4*)(&Ah[sr][scw]) = rA;     // waits only set-R loads (counted vmcnt)
    *(uint4*)(&Al[sr][scw]) = rL;
    *(uint4*)(&Bh[sr][scw]) = rB0;
    *(uint4*)(&Bh[sr + 128][scw]) = rB1;
    *(uint4*)(&Bl[sr][scw]) = rM0;
    *(uint4*)(&Bl[sr + 128][scw]) = rM1;
    __syncthreads();
    const int kn1 = (kb + 64 < kend) ? kb + 64 : kz;   // fallback: safe addr
    rA  = *(const uint4*)(Ahg + aoff + kn1);
    rL  = *(const uint4*)(Alg + aoff + kn1);
    rB0 = *(const uint4*)(Bhg + b0off + kn1);
    rB1 = *(const uint4*)(Bhg + b1off + kn1);
    rM0 = *(const uint4*)(Blg + b0off + kn1);
    rM1 = *(const uint4*)(Blg + b1off + kn1);
    compute();
    __syncthreads();
    // ---- half 2: consume set S (tile kb+32)
    *(uint4*)(&Ah[sr][scw]) = sA;
    *(uint4*)(&Al[sr][scw]) = sL;
    *(uint4*)(&Bh[sr][scw]) = sB0;
    *(uint4*)(&Bh[sr + 128][scw]) = sB1;
    *(uint4*)(&Bl[sr][scw]) = sM0;
    *(uint4*)(&Bl[sr + 128][scw]) = sM1;
    __syncthreads();
    const int kn2 = (kb + 96 < kend) ? kb + 96 : kz;
    sA  = *(const uint4*)(Ahg + aoff + kn2);
    sL  = *(const uint4*)(Alg + aoff + kn2);
    sB0 = *(const uint4*)(Bhg + b0off + kn2);
    sB1 = *(const uint4*)(Bhg + b1off + kn2);
    sM0 = *(const uint4*)(Blg + b0off + kn2);
    sM1 = *(const uint4*)(Blg + b1off + kn2);
    compute();
    __syncthreads();
  }

  float* Cp = CP + (size_t)bz * ((size_t)NROI * HID);   // bz: swizzled!
  const int ccol = nT + wn + fm;
  const int rbase = mT + wm + (fh << 2);
#pragma unroll
  for (int ti = 0; ti < 2; ++ti)
#pragma unroll
    for (int tj = 0; tj < 2; ++tj)
#pragma unroll
      for (int rg = 0; rg < 16; ++rg) {
        const int row = rbase + ti * 32 + (rg & 3) + 8 * (rg >> 2);
        Cp[(size_t)row * HID + ccol + tj * 32] = acc[ti][tj][rg];
      }
}

// ------------------------------------------------------- FC1 fallback (fp32)
__global__ __launch_bounds__(256) void gemm1_kernel(
    const float* __restrict__ A, const float* __restrict__ B,
    float* __restrict__ CP) {
  __shared__ float As[16][68];
  __shared__ float Bs[16][68];
  const int tid = threadIdx.x;
  const int mTile = blockIdx.y << 6;
  const int nTile = blockIdx.x << 6;
  const int k0 = blockIdx.z * KCHUNK;
  const int ty = tid >> 4, tx = tid & 15;
  const int ar = tid >> 2, ac = (tid & 3) << 2;
  const int br = tid >> 4, bcl = (tid & 15) << 2;
  float acc[4][4] = {};

  for (int kb = k0; kb < k0 + KCHUNK; kb += 16) {
    const float4 av = *(const float4*)(A + (size_t)(mTile + ar) * K1 + kb + ac);
    const float4 bv = *(const float4*)(B + (size_t)(kb + br) * HID + nTile + bcl);
    As[ac + 0][ar] = av.x; As[ac + 1][ar] = av.y;
    As[ac + 2][ar] = av.z; As[ac + 3][ar] = av.w;
    *(float4*)(&Bs[br][bcl]) = bv;
    __syncthreads();
#pragma unroll
    for (int kk = 0; kk < 16; ++kk) {
      const float4 a4 = *(const float4*)(&As[kk][ty << 2]);
      const float4 b4 = *(const float4*)(&Bs[kk][tx << 2]);
      const float aa[4] = {a4.x, a4.y, a4.z, a4.w};
      const float bb4[4] = {b4.x, b4.y, b4.z, b4.w};
#pragma unroll
      for (int i = 0; i < 4; ++i)
#pragma unroll
        for (int j = 0; j < 4; ++j)
          acc[i][j] = fmaf(aa[i], bb4[j], acc[i][j]);
    }
    __syncthreads();
  }
  float* Cp = CP + (size_t)blockIdx.z * (HID * NROI);
#pragma unroll
  for (int i = 0; i < 4; ++i) {
    *(float4*)(Cp + (size_t)(mTile + (ty << 2) + i) * HID + nTile + (tx << 2)) =
        make_float4(acc[i][0], acc[i][1], acc[i][2], acc[i][3]);
  }
}

// reduce 8 K-partials + bias + relu -> H1 as split-bf16 (feeds FC2 MFMA)
__global__ __launch_bounds__(256) void bias_relu_bf16_kernel(
    const float* __restrict__ CP, const float* __restrict__ b1,
    u16* __restrict__ H1h, u16* __restrict__ H1l) {
  const int idx = blockIdx.x * 256 + threadIdx.x;
  float v = b1[idx & (HID - 1)];
#pragma unroll
  for (int z = 0; z < ZSPLIT; ++z) v += CP[(size_t)z * (HID * NROI) + idx];
  v = fmaxf(v, 0.0f);
  const u16 h = f2bf(v);
  H1h[idx] = h;
  H1l[idx] = f2bf(v - bf2f(h));
}

// fp32 variant for the fallback path
__global__ __launch_bounds__(256) void bias_relu_f32_kernel(
    const float* __restrict__ CP, const float* __restrict__ b1,
    float* __restrict__ H1) {
  const int idx = blockIdx.x * 256 + threadIdx.x;
  float v = b1[idx & (HID - 1)];
#pragma unroll
  for (int z = 0; z < ZSPLIT; ++z) v += CP[(size_t)z * (HID * NROI) + idx];
  H1[idx] = fmaxf(v, 0.0f);
}

// reduce 8 K-partials of FC2 + bias + relu -> H2 fp32
__global__ __launch_bounds__(256) void bias_relu2_kernel(
    const float* __restrict__ CP2, const float* __restrict__ b2,
    float* __restrict__ H2) {
  const int idx = blockIdx.x * 256 + threadIdx.x;
  float v = b2[idx & (HID - 1)];
#pragma unroll
  for (int z = 0; z < ZSPLIT2; ++z) v += CP2[(size_t)z * (HID * NROI) + idx];
  H2[idx] = fmaxf(v, 0.0f);
}

// ------------------------------------------------------------- FC2 (K=1024)
// fp32 fallback only (bf16 path uses gemm_mfma_split<HID, KCHUNK2, true>)
__global__ __launch_bounds__(256) void gemm2_kernel(
    const float* __restrict__ A, const float* __restrict__ B,
    const float* __restrict__ bias, float* __restrict__ C) {
  __shared__ float As[16][68];
  __shared__ float Bs[16][68];
  const int tid = threadIdx.x;
  const int mTile = blockIdx.y << 6;
  const int nTile = blockIdx.x << 6;
  const int ty = tid >> 4, tx = tid & 15;
  const int ar = tid >> 2, ac = (tid & 3) << 2;
  const int br = tid >> 4, bcl = (tid & 15) << 2;
  float acc[4][4] = {};

  for (int kb = 0; kb < HID; kb += 16) {
    const float4 av = *(const float4*)(A + (size_t)(mTile + ar) * HID + kb + ac);
    const float4 bv = *(const float4*)(B + (size_t)(kb + br) * HID + nTile + bcl);
    As[ac + 0][ar] = av.x; As[ac + 1][ar] = av.y;
    As[ac + 2][ar] = av.z; As[ac + 3][ar] = av.w;
    *(float4*)(&Bs[br][bcl]) = bv;
    __syncthreads();
#pragma unroll
    for (int kk = 0; kk < 16; ++kk) {
      const float4 a4 = *(const float4*)(&As[kk][ty << 2]);
      const float4 b4 = *(const float4*)(&Bs[kk][tx << 2]);
      const float aa[4] = {a4.x, a4.y, a4.z, a4.w};
      const float bb4[4] = {b4.x, b4.y, b4.z, b4.w};
#pragma unroll
      for (int i = 0; i < 4; ++i)
#pragma unroll
        for (int j = 0; j < 4; ++j)
          acc[i][j] = fmaf(aa[i], bb4[j], acc[i][j]);
    }
    __syncthreads();
  }
#pragma unroll
  for (int i = 0; i < 4; ++i) {
#pragma unroll
    for (int j = 0; j < 4; ++j) {
      float v = acc[i][j] + bias[nTile + (tx << 2) + j];
      acc[i][j] = fmaxf(v, 0.0f);
    }
    *(float4*)(C + (size_t)(mTile + (ty << 2) + i) * HID + nTile + (tx << 2)) =
        make_float4(acc[i][0], acc[i][1], acc[i][2], acc[i][3]);
  }
}

// ------------------- heads: cls+box dots, softmax, decode, candidate arrays
// Candidate layout is CLASS-MAJOR: index = n*MCAND + (k-1)*SPROP + s
__global__ __launch_bounds__(128) void heads_kernel(
    const float* __restrict__ H2m, const float* __restrict__ wc,
    const float* __restrict__ bc, const float* __restrict__ wb,
    const float* __restrict__ bb, const float* __restrict__ props,
    float* __restrict__ BX2, float* __restrict__ NB2,
    float* __restrict__ LV2) {
  const int r = blockIdx.x;
  const int tid = threadIdx.x;
  __shared__ float hrow[HID];
  __shared__ float vals[112];
  __shared__ float red[2];

  for (int i = tid; i < HID; i += 128) hrow[i] = H2m[(size_t)r * HID + i];
  __syncthreads();

  if (tid < 105) {
    float acc;
    if (tid < NCLS) {
      acc = bc[tid];
      for (int kk = 0; kk < HID; ++kk) acc = fmaf(hrow[kk], wc[kk * NCLS + tid], acc);
    } else {
      const int j = tid - NCLS;
      acc = bb[j];
      for (int kk = 0; kk < HID; ++kk) acc = fmaf(hrow[kk], wb[kk * (NCLS * 4) + j], acc);
    }
    vals[tid] = acc;
  }
  __syncthreads();

  if (tid == 0) {
    float m = vals[0];
    for (int k = 1; k < NCLS; ++k) m = fmaxf(m, vals[k]);
    float s = 0.0f;
    for (int k = 0; k < NCLS; ++k) s += expf(vals[k] - m);
    red[0] = m;
    red[1] = 1.0f / s;
  }
  __syncthreads();

  if (tid >= 1 && tid <= 20) {
    const int k = tid;
    const float prob = expf(vals[k] - red[0]) * red[1];

    const float px1 = props[r * 4 + 0], py1 = props[r * 4 + 1];
    const float px2 = props[r * 4 + 2], py2 = props[r * 4 + 3];
    const float pw = px2 - px1, ph = py2 - py1;
    const float pcx = px1 + 0.5f * pw, pcy = py1 + 0.5f * ph;

    const float dx = vals[NCLS + k * 4 + 0] / 10.0f;
    const float dy = vals[NCLS + k * 4 + 1] / 10.0f;
    const float dw = fminf(vals[NCLS + k * 4 + 2] / 5.0f, LOGMAX);
    const float dh = fminf(vals[NCLS + k * 4 + 3] / 5.0f, LOGMAX);

    const float cx = dx * pw + pcx, cy = dy * ph + pcy;
    const float w = expf(dw) * pw, h = expf(dh) * ph;
    float b0 = cx - 0.5f * w, b1c = cy - 0.5f * h;
    float b2 = cx + 0.5f * w, b3 = cy + 0.5f * h;
    b0 = fminf(fmaxf(b0, 0.0f), IMGSZ);
    b1c = fminf(fmaxf(b1c, 0.0f), IMGSZ);
    b2 = fminf(fmaxf(b2, 0.0f), IMGSZ);
    b3 = fminf(fmaxf(b3, 0.0f), IMGSZ);

    const float wv = b2 - b0, hv = b3 - b1c;
    const bool valid = (prob > 0.05f) && (wv >= 0.01f) && (hv >= 0.01f);

    const int n = r >> 9, s = r & 511;
    const int cand = (k - 1) * SPROP + s;     // class-major
    const size_t bi = (size_t)n * MCAND + cand;
    const float off = (float)k * (IMGSZ + 1.0f);

    BX2[bi * 4 + 0] = b0; BX2[bi * 4 + 1] = b1c;
    BX2[bi * 4 + 2] = b2; BX2[bi * 4 + 3] = b3;
    NB2[bi * 4 + 0] = b0 + off; NB2[bi * 4 + 1] = b1c + off;
    NB2[bi * 4 + 2] = b2 + off; NB2[bi * 4 + 3] = b3 + off;
    LV2[bi] = valid ? prob : -1.0f;
  }
}

// ---------------------------------------------- per-(image,class) greedy NMS
// Cross-class IoU == 0 (801*k offsets), so the global greedy restricted to a
// class equals the standalone per-class greedy (proved by induction on picks).
// One wave per (n,c): 512 slots in registers, barrier-free serial loop.
template <int CTRL>
__device__ __forceinline__ void red2(float& v, int& ix) {
  const float tv = __int_as_float(__builtin_amdgcn_update_dpp(
      (int)0xC0000000, __float_as_int(v), CTRL, 0xf, 0xf, false));
  const int ti = __builtin_amdgcn_update_dpp(0x7fffffff, ix, CTRL, 0xf, 0xf, false);
  if (tv > v || (tv == v && ti < ix)) { v = tv; ix = ti; }
}
__device__ __forceinline__ void wave_red2(float& v, int& ix) {
  red2<0x111>(v, ix);  // row_shr:1
  red2<0x112>(v, ix);  // row_shr:2
  red2<0x114>(v, ix);  // row_shr:4
  red2<0x118>(v, ix);  // row_shr:8
  red2<0x142>(v, ix);  // row_bcast:15
  red2<0x143>(v, ix);  // row_bcast:31 -> lane 63 holds winner
}

__global__ __launch_bounds__(64) void nms_class_kernel(
    const float* __restrict__ NB2, const float* __restrict__ LV2,
    float* __restrict__ ksg, int* __restrict__ kig, int* __restrict__ cntg) {
  const int bid = blockIdx.x;           // n*20 + c
  const int lane = threadIdx.x;         // 0..63
  __shared__ float4 lbox[SPROP];        // winner-broadcast copy
  const size_t cb = (size_t)bid * SPROP;

  float lv[8], b0[8], b1[8], b2[8], b3[8], ar[8];
#pragma unroll
  for (int j = 0; j < 8; ++j) {
    const int s = lane + j * 64;
    lv[j] = LV2[cb + s];
    const float4 b = *(const float4*)(NB2 + (cb + s) * 4);
    b0[j] = b.x; b1[j] = b.y; b2[j] = b.z; b3[j] = b.w;
    ar[j] = (b.z - b.x) * (b.w - b.y);
    lbox[s] = b;
  }

  int cnt = 0;
  for (int d = 0; d < NDET; ++d) {
    float bv = -2.0f;
    int bix = 0x7fffffff;
#pragma unroll
    for (int j = 0; j < 8; ++j) {     // j asc => slot asc; strict > keeps lowest
      if (lv[j] > bv) { bv = lv[j]; bix = lane + j * 64; }
    }
    wave_red2(bv, bix);
    const float bv2 = __shfl(bv, 63);
    const int bix2 = __shfl(bix, 63);
    if (bv2 <= 0.05f) break;          // all remaining dead; wave-uniform

    if (lane == 0) {
      ksg[bid * NDET + cnt] = bv2;
      kig[bid * NDET + cnt] = bix2;   // slot within class (0..511)
    }
    ++cnt;

    const float4 wb = lbox[bix2];     // same-wave LDS write->read, waitcnt ok
    const float wa = (wb.z - wb.x) * (wb.w - wb.y);
#pragma unroll
    for (int j = 0; j < 8; ++j) {
      const float xx1 = fmaxf(wb.x, b0[j]);
      const float yy1 = fmaxf(wb.y, b1[j]);
      const float xx2 = fminf(wb.z, b2[j]);
      const float yy2 = fminf(wb.w, b3[j]);
      const float inter = fmaxf(xx2 - xx1, 0.0f) * fmaxf(yy2 - yy1, 0.0f);
      const float iou = inter / (wa + ar[j] - inter + 1e-9f);
      if (iou > 0.5f) lv[j] = -1.0f;
    }
  }
  if (lane == 0) cntg[bid] = cnt;
}

// ------------------------------- merge: top-100 by (score desc, flat-idx asc)
// Global greedy order == keeps sorted by packed priority (scores non-increasing
// along greedy; tied keeps are simultaneously live so argmax first-index rule
// = lowest flat idx). Rank-based selection: zero barriers in the hot loop.
__global__ __launch_bounds__(1024) void nms_merge_kernel(
    const float* __restrict__ ksg, const int* __restrict__ kig,
    const int* __restrict__ cntg, const float* __restrict__ BX2,
    float* __restrict__ out) {
  const int n = blockIdx.x;
  const int tid = threadIdx.x;
  __shared__ int cbase[21];
  __shared__ unsigned long long keys[2000];
  __shared__ float ssc[2000];
  __shared__ int sfl[2000];
  __shared__ float svals[NDET];
  __shared__ int sflat[NDET];

  if (tid == 0) {
    int acc = 0;
    for (int c = 0; c < 20; ++c) { cbase[c] = acc; acc += cntg[n * 20 + c]; }
    cbase[20] = acc;
  }
  __syncthreads();
  const int T = cbase[20];     // <= 2000

  for (int idx = tid; idx < 20 * NDET; idx += 1024) {
    const int c = idx / NDET, e = idx - (idx / NDET) * NDET;
    if (e < cntg[n * 20 + c]) {
      const int pos = cbase[c] + e;
      const float s = ksg[(n * 20 + c) * NDET + e];
      const int slot = kig[(n * 20 + c) * NDET + e];
      const int flat = slot * 20 + c;            // original flat candidate idx
      ssc[pos] = s;
      sfl[pos] = flat;
      keys[pos] = ((unsigned long long)__float_as_uint(s) << 32) |
                  (unsigned long long)(0xFFFFFFFFu - (unsigned)flat);
    }
  }
  __syncthreads();

  float msc[2]; int mfl[2]; unsigned long long mk[2]; int rank[2] = {0, 0};
  bool own[2];
#pragma unroll
  for (int e = 0; e < 2; ++e) {
    const int i = tid + e * 1024;
    own[e] = (i < T);
    if (own[e]) { mk[e] = keys[i]; msc[e] = ssc[i]; mfl[e] = sfl[i]; }
  }
  for (int i = 0; i < T; ++i) {        // LDS broadcast read per iteration
    const unsigned long long k = keys[i];
    if (own[0] && k > mk[0]) ++rank[0];
    if (own[1] && k > mk[1]) ++rank[1];
  }
#pragma unroll
  for (int e = 0; e < 2; ++e)
    if (own[e] && rank[e] < NDET) { svals[rank[e]] = msc[e]; sflat[rank[e]] = mfl[e]; }
  __syncthreads();

  if (tid < NDET) {
    const int m = (T < NDET) ? T : NDET;
    const bool keep = tid < m;
    float sv = 0.0f;
    float4 bx4 = make_float4(0.0f, 0.0f, 0.0f, 0.0f);
    float label = 0.0f;
    if (keep) {
      sv = svals[tid];
      const int flat = sflat[tid];
      const int c = flat % 20, s = flat / 20;
      bx4 = *(const float4*)(BX2 + ((size_t)(n * 20 + c) * SPROP + s) * 4);
      label = (float)(c + 1);
    }
    out[(n * NDET + tid) * 4 + 0] = bx4.x;
    out[(n * NDET + tid) * 4 + 1] = bx4.y;
    out[(n * NDET + tid) * 4 + 2] = bx4.z;
    out[(n * NDET + tid) * 4 + 3] = bx4.w;
    out[NIMG * NDET * 4 + n * NDET + tid] = sv;
    out[NIMG * NDET * 4 + NIMG * NDET + n * NDET + tid] = label;
  }
}

// ---------------------------------------------------------------- launcher
extern "C" void kernel_launch(void* const* d_in, const int* in_sizes, int n_in,
                              void* d_out, int out_size, void* d_ws, size_t ws_size,
                              hipStream_t stream) {
  const float* features  = (const float*)d_in[0];
  const float* proposals = (const float*)d_in[1];
  const float* w1 = (const float*)d_in[2];
  const float* b1 = (const float*)d_in[3];
  const float* w2 = (const float*)d_in[4];
  const float* b2 = (const float*)d_in[5];
  const float* wc = (const float*)d_in[6];
  const float* bc = (const float*)d_in[7];
  const float* wb = (const float*)d_in[8];
  const float* bb = (const float*)d_in[9];

  const size_t XE = (size_t)NROI * K1;
  const size_t WE = (size_t)K1 * HID;
  const size_t FLOATS_TAIL =
      (size_t)ZSPLIT * NROI * HID + 2 * (size_t)NROI * HID + (size_t)NIMG * MCAND * 10;
  const size_t NEED = (XE * 2 + WE * 2) * sizeof(u16) + FLOATS_TAIL * sizeof(float);

  if (ws_size >= NEED) {
    u16* Xhi = (u16*)d_ws;
    u16* Xlo = Xhi + XE;
    u16* Wh  = Xlo + XE;
    u16* Wl  = Wh + WE;
    float* CP  = (float*)(Wl + WE);
    // CP region: 8 partials (33.5 MB); FC2's 8 partials (CP2) alias it —
    // CP is dead after bias_relu_bf16, CP2 written only by the later FC2.
    float* CP2 = CP;
    float* H2  = CP + (size_t)ZSPLIT * NROI * HID;
    float* BX2 = H2 + (size_t)NROI * HID;
    float* NB2 = BX2 + (size_t)NIMG * MCAND * 4;
    float* LV2 = NB2 + (size_t)NIMG * MCAND * 4;
    float* ksg = LV2 + (size_t)NIMG * MCAND;
    int*   kig = (int*)(ksg + (size_t)NIMG * 20 * NDET);
    int*   cntg = kig + (size_t)NIMG * 20 * NDET;
    // H1 hi/lo alias the Xhi region (dead after FC1); W2t hi/lo alias Xlo.
    // Stream order guarantees safety: gemm1 reads X before these are written.
    u16* H1h = Xhi;
    u16* H1l = Xhi + (size_t)NROI * HID;
    u16* W2h = Xlo;
    u16* W2l = Xlo + (size_t)HID * HID;

    convw_kernel<K1><<<dim3(K1 / 64, HID / 64), 256, 0, stream>>>(w1, Wh, Wl);
    roi_kernel<true><<<NROI, 256, 0, stream>>>(features, proposals, nullptr, Xhi, Xlo);
    gemm_mfma_split<K1, KCHUNK, true><<<dim3(4, 8, ZSPLIT), 512, 0, stream>>>(
        Xhi, Xlo, Wh, Wl, CP);
    bias_relu_bf16_kernel<<<(NROI * HID) / 256, 256, 0, stream>>>(CP, b1, H1h, H1l);
    convw_kernel<HID><<<dim3(HID / 64, HID / 64), 256, 0, stream>>>(w2, W2h, W2l);
    gemm_mfma_split<HID, KCHUNK2, true><<<dim3(4, 8, ZSPLIT2), 512, 0, stream>>>(
        H1h, H1l, W2h, W2l, CP2);
    bias_relu2_kernel<<<(NROI * HID) / 256, 256, 0, stream>>>(CP2, b2, H2);
    heads_kernel<<<NROI, 128, 0, stream>>>(H2, wc, bc, wb, bb, proposals,
                                           BX2, NB2, LV2);
    nms_class_kernel<<<NIMG * 20, 64, 0, stream>>>(NB2, LV2, ksg, kig, cntg);
    nms_merge_kernel<<<NIMG, 1024, 0, stream>>>(ksg, kig, cntg, BX2,
                                                (float*)d_out);
  } else {
    float* ws = (float*)d_ws;
    float* X   = ws;
    float* CP  = X + XE;
    float* H1  = CP + (size_t)ZSPLIT * NROI * HID;
    float* H2  = H1 + (size_t)NROI * HID;
    float* BX2 = H2 + (size_t)NROI * HID;
    float* NB2 = BX2 + (size_t)NIMG * MCAND * 4;
    float* LV2 = NB2 + (size_t)NIMG * MCAND * 4;
    float* ksg = LV2 + (size_t)NIMG * MCAND;
    int*   kig = (int*)(ksg + (size_t)NIMG * 20 * NDET);
    int*   cntg = kig + (size_t)NIMG * 20 * NDET;

    roi_kernel<false><<<NROI, 256, 0, stream>>>(features, proposals, X, nullptr, nullptr);
    gemm1_kernel<<<dim3(16, 16, ZSPLIT), 256, 0, stream>>>(X, w1, CP);
    bias_relu_f32_kernel<<<(NROI * HID) / 256, 256, 0, stream>>>(CP, b1, H1);
    gemm2_kernel<<<dim3(16, 16), 256, 0, stream>>>(H1, w2, b2, H2);
    heads_kernel<<<NROI, 128, 0, stream>>>(H2, wc, bc, wb, bb, proposals,
                                           BX2, NB2, LV2);
    nms_class_kernel<<<NIMG * 20, 64, 0, stream>>>(NB2, LV2, ksg, kig, cntg);
    nms_merge_kernel<<<NIMG, 1024, 0, stream>>>(ksg, kig, cntg, BX2,
                                                (float*)d_out);
  }
}